// Round 2
// baseline (2351.634 us; speedup 1.0000x reference)
//
#include <hip/hip_runtime.h>

typedef unsigned short u16;
typedef unsigned int u32;

constexpr int Bc = 2, Sc = 2048, Dc = 2048, Hc = 16, HDc = 128;

using short8 = __attribute__((ext_vector_type(8))) short;
using f32x4v = __attribute__((ext_vector_type(4))) float;

static __device__ __forceinline__ float bf2f(u16 v) { return __uint_as_float(((u32)v) << 16); }
static __device__ __forceinline__ u16 f2bf(float f) {
    u32 u = __float_as_uint(f);
    return (u16)((u + 0x7fffu + ((u >> 16) & 1u)) >> 16);
}
static __device__ __forceinline__ void unpack2(u32 w, float& lo, float& hi) {
    lo = __uint_as_float(w << 16);
    hi = __uint_as_float(w & 0xffff0000u);
}

// ---------------- fp32 -> bf16 bulk convert ----------------
__global__ __launch_bounds__(256) void cvt_k(const float* __restrict__ in, u16* __restrict__ out, int n) {
    int i = (blockIdx.x * 256 + threadIdx.x) * 8;
    if (i >= n) return;
    float4 a = *(const float4*)(in + i);
    float4 b = *(const float4*)(in + i + 4);
    u16 r[8] = {f2bf(a.x), f2bf(a.y), f2bf(a.z), f2bf(a.w),
                f2bf(b.x), f2bf(b.y), f2bf(b.z), f2bf(b.w)};
    *(uint4*)(out + i) = *(uint4*)r;
}

// ---------------- fp32 W (R x C) -> bf16 Wt (C x R) transpose+convert ----------------
__global__ __launch_bounds__(256) void tcvt_k(const float* __restrict__ in, u16* __restrict__ out,
                                              int R, int C) {
    __shared__ u16 tile[32][33];
    int bx = blockIdx.x * 32, by = blockIdx.y * 32;
    int tx = threadIdx.x & 31, ty = threadIdx.x >> 5;
    #pragma unroll
    for (int i = ty; i < 32; i += 8) tile[i][tx] = f2bf(in[(size_t)(by + i) * C + bx + tx]);
    __syncthreads();
    #pragma unroll
    for (int i = ty; i < 32; i += 8) out[(size_t)(bx + i) * R + by + tx] = tile[tx][i];
}

// ---------------- bf16 MFMA GEMM: C = A(MxK) * B(KxN), Bt is N x K ----------------
// MODE 1: bf16 out, (B,H,S,HD) scatter layout   (Q, K, V projections)
// MODE 2: fp32 out, row-major M x N             (output projection -> d_out)
template <int MODE>
__global__ __launch_bounds__(256) void gemm_bt(const u16* __restrict__ A, const u16* __restrict__ Bt,
                                               void* __restrict__ Cout, int M, int N, int K) {
    constexpr int LDT = 40; // padded LDS row (u16); 80B stride, 16B-aligned
    __shared__ u16 As[64 * LDT];
    __shared__ u16 Bs[64 * LDT];
    int m0 = blockIdx.y * 64, n0 = blockIdx.x * 64;
    int t = threadIdx.x;
    int wv = t >> 6, lane = t & 63;
    int wr = wv >> 1, wc = wv & 1;
    int fm = lane & 15, fk = (lane >> 4) * 8;
    f32x4v acc[2][2] = {};

    int lr = t >> 2, lc = (t & 3) * 8;
    const u16* Aw = A + (size_t)(m0 + lr) * K + lc;
    const u16* Bw = Bt + (size_t)(n0 + lr) * K + lc;
    u16* AsW = &As[lr * LDT + lc];
    u16* BsW = &Bs[lr * LDT + lc];
    const u16* ap0 = &As[(wr * 32 + fm) * LDT + fk];
    const u16* bp0 = &Bs[(wc * 32 + fm) * LDT + fk];

    for (int kk = 0; kk < K; kk += 32) {
        uint4 av = *(const uint4*)(Aw + kk);
        uint4 bv = *(const uint4*)(Bw + kk);
        __syncthreads();
        *(uint4*)AsW = av;
        *(uint4*)BsW = bv;
        __syncthreads();
        short8 a0 = *(const short8*)ap0;
        short8 a1 = *(const short8*)(ap0 + 16 * LDT);
        short8 b0 = *(const short8*)bp0;
        short8 b1 = *(const short8*)(bp0 + 16 * LDT);
        acc[0][0] = __builtin_amdgcn_mfma_f32_16x16x32_bf16(a0, b0, acc[0][0], 0, 0, 0);
        acc[0][1] = __builtin_amdgcn_mfma_f32_16x16x32_bf16(a0, b1, acc[0][1], 0, 0, 0);
        acc[1][0] = __builtin_amdgcn_mfma_f32_16x16x32_bf16(a1, b0, acc[1][0], 0, 0, 0);
        acc[1][1] = __builtin_amdgcn_mfma_f32_16x16x32_bf16(a1, b1, acc[1][1], 0, 0, 0);
    }

    int rb = m0 + wr * 32 + ((lane >> 4) << 2);
    int cb = n0 + wc * 32 + fm;
    #pragma unroll
    for (int mt = 0; mt < 2; ++mt)
        #pragma unroll
        for (int nt = 0; nt < 2; ++nt) {
            #pragma unroll
            for (int r = 0; r < 4; ++r) {
                int m = rb + mt * 16 + r;
                int n = cb + nt * 16;
                float v = acc[mt][nt][r];
                if (MODE == 2) {
                    ((float*)Cout)[(size_t)m * N + n] = v;
                } else {
                    int b = m >> 11, s = m & (Sc - 1);   // M rows = b*S + s
                    int h = n >> 7, d = n & (HDc - 1);   // N cols = h*HD + d
                    size_t idx = (((size_t)b * Hc + h) * Sc + s) * HDc + d;
                    ((u16*)Cout)[idx] = f2bf(v);
                }
            }
        }
}

// ---------------- RoPE in place on bf16 (B,H,S,HD) buffer ----------------
__global__ __launch_bounds__(256) void rope_k(u16* __restrict__ buf, int nrows) {
    int idx = blockIdx.x * 256 + threadIdx.x;
    int row = idx >> 6, i = idx & 63;
    if (row >= nrows) return;
    int s = row & (Sc - 1); // row = (b*H+h)*S + s
    u16* p = buf + (size_t)row * HDc + i;
    float x1 = bf2f(p[0]), x2 = bf2f(p[64]);
    float freq = powf(10000.0f, -(float)i * (1.0f / 64.0f));
    float ang = (float)s * freq;
    float c, sn;
    sincosf(ang, &sn, &c);
    p[0]  = f2bf(x1 * c - x2 * sn);
    p[64] = f2bf(x2 * c + x1 * sn);
}

// ---------------- causal attention, one wave per 4 queries ----------------
// Q,K,V bf16 (B,H,S,HD); ctx bf16 (B,S,H,HD)
__global__ __launch_bounds__(256) void attn_k(const u16* __restrict__ Q, const u16* __restrict__ K,
                                              const u16* __restrict__ V, u16* __restrict__ ctx) {
    __shared__ float qs[4][4][HDc]; // [wave-in-block][query][dim], pre-scaled
    int wid = threadIdx.x >> 6, lane = threadIdx.x & 63;
    int wave = blockIdx.x * 4 + wid;
    int qg = wave & (Sc / 4 - 1);
    int bh = wave >> 9; // wave / (Sc/4)
    int q0 = qg << 2;
    const u16* Qb = Q + ((size_t)bh * Sc + q0) * HDc;
    const u16* Kb = K + (size_t)bh * Sc * HDc;
    const u16* Vb = V + (size_t)bh * Sc * HDc;
    {
        int qi = lane >> 4, d0 = (lane & 15) * 8;
        uint4 qv = *(const uint4*)(Qb + qi * HDc + d0);
        float f[8];
        unpack2(qv.x, f[0], f[1]); unpack2(qv.y, f[2], f[3]);
        unpack2(qv.z, f[4], f[5]); unpack2(qv.w, f[6], f[7]);
        const float sc = 0.08838834764831845f; // 1/sqrt(128)
        #pragma unroll
        for (int e = 0; e < 8; ++e) qs[wid][qi][d0 + e] = f[e] * sc;
    }
    __syncthreads();

    float mi[4], li[4], aa[4], ab[4], pv[4];
    #pragma unroll
    for (int i = 0; i < 4; ++i) { mi[i] = -1e30f; li[i] = 0.f; aa[i] = 0.f; ab[i] = 0.f; }
    const float* qp0 = &qs[wid][0][0];
    const float* qp1 = &qs[wid][1][0];
    const float* qp2 = &qs[wid][2][0];
    const float* qp3 = &qs[wid][3][0];
    int jmax = q0 + 3;

    for (int j0 = 0; j0 <= jmax; j0 += 64) {
        int j = j0 + lane;
        const u16* Kr = Kb + (size_t)j * HDc; // j <= 2047 always in valid region
        float s0 = 0, s1 = 0, s2 = 0, s3 = 0;
        #pragma unroll 4
        for (int d = 0; d < HDc; d += 8) {
            uint4 kv = *(const uint4*)(Kr + d);
            float kf[8];
            unpack2(kv.x, kf[0], kf[1]); unpack2(kv.y, kf[2], kf[3]);
            unpack2(kv.z, kf[4], kf[5]); unpack2(kv.w, kf[6], kf[7]);
            float4 qa0 = *(const float4*)(qp0 + d), qa1 = *(const float4*)(qp0 + d + 4);
            float4 qb0 = *(const float4*)(qp1 + d), qb1 = *(const float4*)(qp1 + d + 4);
            float4 qc0 = *(const float4*)(qp2 + d), qc1 = *(const float4*)(qp2 + d + 4);
            float4 qd0 = *(const float4*)(qp3 + d), qd1 = *(const float4*)(qp3 + d + 4);
            s0 += qa0.x*kf[0] + qa0.y*kf[1] + qa0.z*kf[2] + qa0.w*kf[3]
                + qa1.x*kf[4] + qa1.y*kf[5] + qa1.z*kf[6] + qa1.w*kf[7];
            s1 += qb0.x*kf[0] + qb0.y*kf[1] + qb0.z*kf[2] + qb0.w*kf[3]
                + qb1.x*kf[4] + qb1.y*kf[5] + qb1.z*kf[6] + qb1.w*kf[7];
            s2 += qc0.x*kf[0] + qc0.y*kf[1] + qc0.z*kf[2] + qc0.w*kf[3]
                + qc1.x*kf[4] + qc1.y*kf[5] + qc1.z*kf[6] + qc1.w*kf[7];
            s3 += qd0.x*kf[0] + qd0.y*kf[1] + qd0.z*kf[2] + qd0.w*kf[3]
                + qd1.x*kf[4] + qd1.y*kf[5] + qd1.z*kf[6] + qd1.w*kf[7];
        }
        float sv[4];
        sv[0] = (j <= q0)     ? s0 : -1e30f;
        sv[1] = (j <= q0 + 1) ? s1 : -1e30f;
        sv[2] = (j <= q0 + 2) ? s2 : -1e30f;
        sv[3] = (j <= jmax)   ? s3 : -1e30f;
        #pragma unroll
        for (int i = 0; i < 4; ++i) {
            float cm = sv[i];
            #pragma unroll
            for (int off = 32; off > 0; off >>= 1) cm = fmaxf(cm, __shfl_xor(cm, off, 64));
            float mn = fmaxf(mi[i], cm);
            float al = __expf(mi[i] - mn); // mi=-1e30 initially -> 0
            float p = __expf(sv[i] - mn);  // masked lanes -> 0
            float sp = p;
            #pragma unroll
            for (int off = 32; off > 0; off >>= 1) sp += __shfl_xor(sp, off, 64);
            li[i] = li[i] * al + sp;
            mi[i] = mn;
            aa[i] *= al;
            ab[i] *= al;
            pv[i] = p;
        }
        int nv = jmax - j0 + 1;
        if (nv > 64) nv = 64;
        const u16* Vr = Vb + (size_t)j0 * HDc + 2 * lane;
        for (int jj = 0; jj < nv; ++jj) {
            u32 vvv = *(const u32*)Vr;
            Vr += HDc;
            float v0, v1;
            unpack2(vvv, v0, v1);
            float b0 = __shfl(pv[0], jj, 64);
            float b1 = __shfl(pv[1], jj, 64);
            float b2 = __shfl(pv[2], jj, 64);
            float b3 = __shfl(pv[3], jj, 64);
            aa[0] += b0 * v0; ab[0] += b0 * v1;
            aa[1] += b1 * v0; ab[1] += b1 * v1;
            aa[2] += b2 * v0; ab[2] += b2 * v1;
            aa[3] += b3 * v0; ab[3] += b3 * v1;
        }
    }

    int b = bh >> 4, h = bh & 15;
    #pragma unroll
    for (int i = 0; i < 4; ++i) {
        float inv = 1.0f / li[i];
        u32 lo = f2bf(aa[i] * inv);
        u32 hi = f2bf(ab[i] * inv);
        *(u32*)(ctx + (((size_t)(b * Sc + q0 + i)) * Hc + h) * HDc + 2 * lane) = lo | (hi << 16);
    }
}

extern "C" void kernel_launch(void* const* d_in, const int* in_sizes, int n_in,
                              void* d_out, int out_size, void* d_ws, size_t ws_size,
                              hipStream_t stream) {
    (void)in_sizes; (void)n_in; (void)out_size; (void)ws_size;
    const float* x  = (const float*)d_in[0];
    // d_in[1] = mask: causal tril, handled analytically in-kernel
    const float* Wq = (const float*)d_in[2];
    const float* Wk = (const float*)d_in[3];
    const float* Wv = (const float*)d_in[4];
    const float* Wo = (const float*)d_in[5];

    // workspace layout (72 MiB total)
    char* w = (char*)d_ws;
    u16* Wt  = (u16*)w; w += (size_t)Dc * Dc * 2;            //  8 MiB, reused 4x
    u16* Qb  = (u16*)w; w += (size_t)Bc * Hc * Sc * HDc * 2; // 16 MiB
    u16* Kb  = (u16*)w; w += (size_t)Bc * Hc * Sc * HDc * 2;
    u16* Vb  = (u16*)w; w += (size_t)Bc * Hc * Sc * HDc * 2;
    u16* ctx = (u16*)w; w += (size_t)Bc * Sc * Hc * HDc * 2;
    // bf16 copy of x lives in the (currently unused) d_out buffer (fp32, 32 MiB)
    u16* xb = (u16*)d_out;

    int nx = Bc * Sc * Dc;
    cvt_k<<<dim3(nx / 2048), 256, 0, stream>>>(x, xb, nx);

    dim3 tgrid(Dc / 32, Dc / 32);
    dim3 ggrid(Dc / 64, (Bc * Sc) / 64); // N-tiles x M-tiles

    tcvt_k<<<tgrid, 256, 0, stream>>>(Wq, Wt, Dc, Dc);
    gemm_bt<1><<<ggrid, 256, 0, stream>>>(xb, Wt, (void*)Qb, Bc * Sc, Dc, Dc);
    tcvt_k<<<tgrid, 256, 0, stream>>>(Wk, Wt, Dc, Dc);
    gemm_bt<1><<<ggrid, 256, 0, stream>>>(xb, Wt, (void*)Kb, Bc * Sc, Dc, Dc);
    tcvt_k<<<tgrid, 256, 0, stream>>>(Wv, Wt, Dc, Dc);
    gemm_bt<1><<<ggrid, 256, 0, stream>>>(xb, Wt, (void*)Vb, Bc * Sc, Dc, Dc);

    int nrows = Bc * Hc * Sc;
    rope_k<<<dim3(nrows * 64 / 256), 256, 0, stream>>>(Qb, nrows);
    rope_k<<<dim3(nrows * 64 / 256), 256, 0, stream>>>(Kb, nrows);

    attn_k<<<dim3(Bc * Hc * (Sc / 4) / 4), 256, 0, stream>>>(Qb, Kb, Vb, ctx);

    tcvt_k<<<tgrid, 256, 0, stream>>>(Wo, Wt, Dc, Dc);
    gemm_bt<2><<<ggrid, 256, 0, stream>>>(ctx, Wt, d_out, Bc * Sc, Dc, Dc);
}

// Round 3
// 775.775 us; speedup vs baseline: 3.0313x; 3.0313x over previous
//
#include <hip/hip_runtime.h>

typedef unsigned short u16;
typedef unsigned int u32;

constexpr int Bc = 2, Sc = 2048, Dc = 2048, Hc = 16, HDc = 128;

using short8 = __attribute__((ext_vector_type(8))) short;
using f32x4v = __attribute__((ext_vector_type(4))) float;

static __device__ __forceinline__ float bf2f(u16 v) { return __uint_as_float(((u32)v) << 16); }
static __device__ __forceinline__ u16 f2bf(float f) {
    u32 u = __float_as_uint(f);
    return (u16)((u + 0x7fffu + ((u >> 16) & 1u)) >> 16);
}

// async global->LDS, 16B per lane; LDS dest = wave-uniform base + lane*16
__device__ __forceinline__ void gll16(const u16* g, u16* l) {
    __builtin_amdgcn_global_load_lds((const __attribute__((address_space(1))) void*)g,
                                     (__attribute__((address_space(3))) void*)l, 16, 0, 0);
}

// ---------------- fp32 -> bf16 bulk convert ----------------
__global__ __launch_bounds__(256) void cvt_k(const float* __restrict__ in, u16* __restrict__ out, int n) {
    int i = (blockIdx.x * 256 + threadIdx.x) * 8;
    if (i >= n) return;
    float4 a = *(const float4*)(in + i);
    float4 b = *(const float4*)(in + i + 4);
    u16 r[8] = {f2bf(a.x), f2bf(a.y), f2bf(a.z), f2bf(a.w),
                f2bf(b.x), f2bf(b.y), f2bf(b.z), f2bf(b.w)};
    *(uint4*)(out + i) = *(uint4*)r;
}

// ---------------- fp32 W (R x C) -> bf16 Wt (C x R) transpose+convert ----------------
__global__ __launch_bounds__(256) void tcvt_k(const float* __restrict__ in, u16* __restrict__ out,
                                              int R, int C) {
    __shared__ u16 tile[32][33];
    int bx = blockIdx.x * 32, by = blockIdx.y * 32;
    int tx = threadIdx.x & 31, ty = threadIdx.x >> 5;
    #pragma unroll
    for (int i = ty; i < 32; i += 8) tile[i][tx] = f2bf(in[(size_t)(by + i) * C + bx + tx]);
    __syncthreads();
    #pragma unroll
    for (int i = ty; i < 32; i += 8) out[(size_t)(bx + i) * R + by + tx] = tile[tx][i];
}

// ---------------- bf16 MFMA GEMM, 128x128 tile, BK=32, global_load_lds staging -------
// C = A(MxK) * B(KxN), Bt is N x K row-major.
// MODE 1: bf16 out, (B,H,S,HD) scatter      (Q, K projections)
// MODE 2: fp32 out, row-major M x N         (output projection -> d_out)
// MODE 3: bf16 out, (B,H,HD,S) scatter      (V projection, transposed)
template <int MODE>
__global__ __launch_bounds__(256) void gemm_bt(const u16* __restrict__ A, const u16* __restrict__ Bt,
                                               void* __restrict__ Cout, int M, int N, int K) {
    __shared__ u16 As[128 * 32];
    __shared__ u16 Bs[128 * 32];
    int m0 = blockIdx.y * 128, n0 = blockIdx.x * 128;
    int t = threadIdx.x;
    int wid = t >> 6, lane = t & 63;
    int wr = wid >> 1, wc = wid & 1;
    f32x4v acc[4][4] = {};

    // staging map: chunk c (16B) -> row c>>2, col (c&3)*8
    int c0 = wid * 128 + lane;          // tt=0
    int c1 = wid * 128 + 64 + lane;     // tt=1
    const u16* Ar0 = A + (size_t)(m0 + (c0 >> 2)) * K + (c0 & 3) * 8;
    const u16* Ar1 = A + (size_t)(m0 + (c1 >> 2)) * K + (c1 & 3) * 8;
    const u16* Br0 = Bt + (size_t)(n0 + (c0 >> 2)) * K + (c0 & 3) * 8;
    const u16* Br1 = Bt + (size_t)(n0 + (c1 >> 2)) * K + (c1 & 3) * 8;
    u16* Al0 = As + (wid * 128) * 8;
    u16* Al1 = As + (wid * 128 + 64) * 8;
    u16* Bl0 = Bs + (wid * 128) * 8;
    u16* Bl1 = Bs + (wid * 128 + 64) * 8;

    const u16* ap = As + (wr * 64 + (lane & 15)) * 32 + (lane >> 4) * 8;
    const u16* bp = Bs + (wc * 64 + (lane & 15)) * 32 + (lane >> 4) * 8;

    for (int kk = 0; kk < K; kk += 32) {
        gll16(Ar0 + kk, Al0);
        gll16(Ar1 + kk, Al1);
        gll16(Br0 + kk, Bl0);
        gll16(Br1 + kk, Bl1);
        __syncthreads();
        short8 a[4], b[4];
        #pragma unroll
        for (int i = 0; i < 4; ++i) {
            a[i] = *(const short8*)(ap + i * 512);
            b[i] = *(const short8*)(bp + i * 512);
        }
        #pragma unroll
        for (int mf = 0; mf < 4; ++mf)
            #pragma unroll
            for (int nf = 0; nf < 4; ++nf)
                acc[mf][nf] = __builtin_amdgcn_mfma_f32_16x16x32_bf16(a[mf], b[nf], acc[mf][nf], 0, 0, 0);
        __syncthreads();
    }

    int rb = m0 + wr * 64 + ((lane >> 4) << 2);
    int cb = n0 + wc * 64 + (lane & 15);
    #pragma unroll
    for (int mf = 0; mf < 4; ++mf)
        #pragma unroll
        for (int nf = 0; nf < 4; ++nf)
            #pragma unroll
            for (int r = 0; r < 4; ++r) {
                int m = rb + mf * 16 + r;
                int n = cb + nf * 16;
                float v = acc[mf][nf][r];
                if (MODE == 2) {
                    ((float*)Cout)[(size_t)m * N + n] = v;
                } else {
                    int b_ = m >> 11, s = m & (Sc - 1);
                    int h = n >> 7, d = n & (HDc - 1);
                    size_t idx;
                    if (MODE == 1) idx = (((size_t)b_ * Hc + h) * Sc + s) * HDc + d;
                    else           idx = (((size_t)b_ * Hc + h) * HDc + d) * Sc + s;
                    ((u16*)Cout)[idx] = f2bf(v);
                }
            }
}

// ---------------- RoPE in place on bf16 (B,H,S,HD) buffer ----------------
__global__ __launch_bounds__(256) void rope_k(u16* __restrict__ buf, int nrows) {
    int idx = blockIdx.x * 256 + threadIdx.x;
    int row = idx >> 6, i = idx & 63;
    if (row >= nrows) return;
    int s = row & (Sc - 1);
    u16* p = buf + (size_t)row * HDc + i;
    float x1 = bf2f(p[0]), x2 = bf2f(p[64]);
    float freq = powf(10000.0f, -(float)i * (1.0f / 64.0f));
    float ang = (float)s * freq;
    float c, sn;
    sincosf(ang, &sn, &c);
    p[0]  = f2bf(x1 * c - x2 * sn);
    p[64] = f2bf(x2 * c + x1 * sn);
}

// ---------------- MFMA flash attention ----------------
// Q,K bf16 (B,H,S,HD); Vt bf16 (B,H,HD,S); ctx bf16 (B,S,H,HD)
// grid (S/128, B*H), 256 threads. Each wave owns 32 query rows, fully independent.
__global__ __launch_bounds__(256) void fattn_k(const u16* __restrict__ Q, const u16* __restrict__ K,
                                               const u16* __restrict__ Vt, u16* __restrict__ ctx) {
    constexpr int LDP = 72; // padded P row (u16)
    __shared__ u16 Ps[4][32][LDP];
    int wid = threadIdx.x >> 6, lane = threadIdx.x & 63;
    int bh = blockIdx.y;
    int wrow0 = blockIdx.x * 128 + wid * 32;
    const u16* Qb = Q + ((size_t)bh * Sc + wrow0) * HDc;
    const u16* Kb = K + (size_t)bh * Sc * HDc;
    const u16* Vb = Vt + (size_t)bh * HDc * Sc;
    int ln = lane & 15, lq = lane >> 4;

    // Q A-frags: A[m=ln][k=lq*8+e], m-frags mf*16, k-steps ks*32
    short8 aq[2][4];
    #pragma unroll
    for (int mf = 0; mf < 2; ++mf)
        #pragma unroll
        for (int ks = 0; ks < 4; ++ks)
            aq[mf][ks] = *(const short8*)(Qb + (size_t)(mf * 16 + ln) * HDc + ks * 32 + lq * 8);

    f32x4v o[2][8] = {};
    float mr[8], lr[8];
    #pragma unroll
    for (int i = 0; i < 8; ++i) { mr[i] = -1e30f; lr[i] = 0.f; }

    const float sc = 0.08838834764831845f; // 1/sqrt(128)
    int jend = wrow0 + 31;
    for (int j0 = 0; j0 <= jend; j0 += 64) {
        // ---- S = Q K^T ----
        f32x4v sf[2][4] = {};
        #pragma unroll
        for (int ks = 0; ks < 4; ++ks)
            #pragma unroll
            for (int nf = 0; nf < 4; ++nf) {
                short8 bk = *(const short8*)(Kb + (size_t)(j0 + nf * 16 + ln) * HDc + ks * 32 + lq * 8);
                sf[0][nf] = __builtin_amdgcn_mfma_f32_16x16x32_bf16(aq[0][ks], bk, sf[0][nf], 0, 0, 0);
                sf[1][nf] = __builtin_amdgcn_mfma_f32_16x16x32_bf16(aq[1][ks], bk, sf[1][nf], 0, 0, 0);
            }

        bool diag = (j0 + 63 > wrow0);
        // ---- online softmax (C layout: row = lq*4+r, col = ln) ----
        #pragma unroll
        for (int mf = 0; mf < 2; ++mf) {
            int rowb = wrow0 + mf * 16 + (lq << 2);
            float sv[4][4];
            #pragma unroll
            for (int nf = 0; nf < 4; ++nf)
                #pragma unroll
                for (int r = 0; r < 4; ++r) {
                    float s = sf[mf][nf][r] * sc;
                    if (diag) {
                        int j = j0 + nf * 16 + ln;
                        if (j > rowb + r) s = -1e30f;
                    }
                    sv[nf][r] = s;
                }
            #pragma unroll
            for (int r = 0; r < 4; ++r) {
                float mx = fmaxf(fmaxf(sv[0][r], sv[1][r]), fmaxf(sv[2][r], sv[3][r]));
                #pragma unroll
                for (int off = 1; off < 16; off <<= 1) mx = fmaxf(mx, __shfl_xor(mx, off, 64));
                float mo = mr[mf * 4 + r];
                float mn = fmaxf(mo, mx);
                float al = __expf(mo - mn);
                mr[mf * 4 + r] = mn;
                float ps = 0.f;
                #pragma unroll
                for (int nf = 0; nf < 4; ++nf) {
                    float p = __expf(sv[nf][r] - mn);
                    sv[nf][r] = p;
                    ps += p;
                }
                #pragma unroll
                for (int off = 1; off < 16; off <<= 1) ps += __shfl_xor(ps, off, 64);
                lr[mf * 4 + r] = lr[mf * 4 + r] * al + ps;
                #pragma unroll
                for (int nd = 0; nd < 8; ++nd) o[mf][nd][r] *= al;
            }
            #pragma unroll
            for (int nf = 0; nf < 4; ++nf)
                #pragma unroll
                for (int r = 0; r < 4; ++r)
                    Ps[wid][mf * 16 + (lq << 2) + r][nf * 16 + ln] = f2bf(sv[nf][r]);
        }

        // ---- O += P V ----  (A from LDS strip, B direct from global Vt)
        short8 ap0[2][2];
        #pragma unroll
        for (int mf = 0; mf < 2; ++mf)
            #pragma unroll
            for (int ks = 0; ks < 2; ++ks)
                ap0[mf][ks] = *(const short8*)&Ps[wid][mf * 16 + ln][ks * 32 + lq * 8];
        #pragma unroll
        for (int ks = 0; ks < 2; ++ks)
            #pragma unroll
            for (int nd = 0; nd < 8; ++nd) {
                short8 bv = *(const short8*)(Vb + (size_t)(nd * 16 + ln) * Sc + j0 + ks * 32 + lq * 8);
                o[0][nd] = __builtin_amdgcn_mfma_f32_16x16x32_bf16(ap0[0][ks], bv, o[0][nd], 0, 0, 0);
                o[1][nd] = __builtin_amdgcn_mfma_f32_16x16x32_bf16(ap0[1][ks], bv, o[1][nd], 0, 0, 0);
            }
    }

    // ---- normalize + write ctx (B,S,H,HD) ----
    int b = bh >> 4, h = bh & 15;
    #pragma unroll
    for (int mf = 0; mf < 2; ++mf)
        #pragma unroll
        for (int r = 0; r < 4; ++r) {
            float inv = 1.0f / lr[mf * 4 + r];
            int q = wrow0 + mf * 16 + (lq << 2) + r;
            u16* cp = ctx + (((size_t)(b * Sc + q)) * Hc + h) * HDc + ln;
            #pragma unroll
            for (int nd = 0; nd < 8; ++nd)
                cp[nd * 16] = f2bf(o[mf][nd][r] * inv);
        }
}

extern "C" void kernel_launch(void* const* d_in, const int* in_sizes, int n_in,
                              void* d_out, int out_size, void* d_ws, size_t ws_size,
                              hipStream_t stream) {
    (void)in_sizes; (void)n_in; (void)out_size; (void)ws_size;
    const float* x  = (const float*)d_in[0];
    // d_in[1] = mask: causal, handled analytically
    const float* Wq = (const float*)d_in[2];
    const float* Wk = (const float*)d_in[3];
    const float* Wv = (const float*)d_in[4];
    const float* Wo = (const float*)d_in[5];

    char* w = (char*)d_ws;
    u16* Wt  = (u16*)w; w += (size_t)Dc * Dc * 2;            //  8 MiB, reused 4x
    u16* Qb  = (u16*)w; w += (size_t)Bc * Hc * Sc * HDc * 2; // 16 MiB
    u16* Kb  = (u16*)w; w += (size_t)Bc * Hc * Sc * HDc * 2;
    u16* Vb  = (u16*)w; w += (size_t)Bc * Hc * Sc * HDc * 2; // V^T (B,H,HD,S)
    u16* ctx = (u16*)w; w += (size_t)Bc * Sc * Hc * HDc * 2;
    u16* xb = (u16*)d_out; // bf16 x in d_out scratch (fp32 out = 2x the bytes)

    int nx = Bc * Sc * Dc;
    cvt_k<<<dim3(nx / 2048), 256, 0, stream>>>(x, xb, nx);

    dim3 tgrid(Dc / 32, Dc / 32);
    dim3 ggrid(Dc / 128, (Bc * Sc) / 128);

    tcvt_k<<<tgrid, 256, 0, stream>>>(Wq, Wt, Dc, Dc);
    gemm_bt<1><<<ggrid, 256, 0, stream>>>(xb, Wt, (void*)Qb, Bc * Sc, Dc, Dc);
    tcvt_k<<<tgrid, 256, 0, stream>>>(Wk, Wt, Dc, Dc);
    gemm_bt<1><<<ggrid, 256, 0, stream>>>(xb, Wt, (void*)Kb, Bc * Sc, Dc, Dc);
    tcvt_k<<<tgrid, 256, 0, stream>>>(Wv, Wt, Dc, Dc);
    gemm_bt<3><<<ggrid, 256, 0, stream>>>(xb, Wt, (void*)Vb, Bc * Sc, Dc, Dc);

    int nrows = Bc * Hc * Sc;
    rope_k<<<dim3(nrows * 64 / 256), 256, 0, stream>>>(Qb, nrows);
    rope_k<<<dim3(nrows * 64 / 256), 256, 0, stream>>>(Kb, nrows);

    fattn_k<<<dim3(Sc / 128, Bc * Hc), 256, 0, stream>>>(Qb, Kb, Vb, ctx);

    tcvt_k<<<tgrid, 256, 0, stream>>>(Wo, Wt, Dc, Dc);
    gemm_bt<2><<<ggrid, 256, 0, stream>>>(ctx, Wt, d_out, Bc * Sc, Dc, Dc);
}

// Round 4
// 610.300 us; speedup vs baseline: 3.8532x; 1.2711x over previous
//
#include <hip/hip_runtime.h>

typedef unsigned short u16;
typedef unsigned int u32;

constexpr int Bc = 2, Sc = 2048, Dc = 2048, Hc = 16, HDc = 128;

using short8 = __attribute__((ext_vector_type(8))) short;
using f32x4v = __attribute__((ext_vector_type(4))) float;

static __device__ __forceinline__ float bf2f(u16 v) { return __uint_as_float(((u32)v) << 16); }
static __device__ __forceinline__ u16 f2bf(float f) {
    u32 u = __float_as_uint(f);
    return (u16)((u + 0x7fffu + ((u >> 16) & 1u)) >> 16);
}

// async global->LDS, 16B per lane; LDS dest = wave-uniform base + lane*16
__device__ __forceinline__ void gll16(const u16* g, u16* l) {
    __builtin_amdgcn_global_load_lds((const __attribute__((address_space(1))) void*)g,
                                     (__attribute__((address_space(3))) void*)l, 16, 0, 0);
}

// ---------------- fp32 -> bf16 bulk convert ----------------
__global__ __launch_bounds__(256) void cvt_k(const float* __restrict__ in, u16* __restrict__ out, int n) {
    int i = (blockIdx.x * 256 + threadIdx.x) * 8;
    if (i >= n) return;
    float4 a = *(const float4*)(in + i);
    float4 b = *(const float4*)(in + i + 4);
    u16 r[8] = {f2bf(a.x), f2bf(a.y), f2bf(a.z), f2bf(a.w),
                f2bf(b.x), f2bf(b.y), f2bf(b.z), f2bf(b.w)};
    *(uint4*)(out + i) = *(uint4*)r;
}

// ---------------- fp32 W (R x C) -> bf16 Wt (C x R), 64x64 tiles, vectorized ----------------
__global__ __launch_bounds__(256) void tcvt_k(const float* __restrict__ in, u16* __restrict__ out,
                                              int R, int C) {
    __shared__ u16 tile[64][68];
    int bx = blockIdx.x * 64, by = blockIdx.y * 64;
    int t = threadIdx.x;
    int r = t >> 4, c4 = (t & 15) * 4;
    #pragma unroll
    for (int i = 0; i < 4; ++i) {
        int row = by + r + i * 16;
        float4 v = *(const float4*)(in + (size_t)row * C + bx + c4);
        u16* d = &tile[r + i * 16][c4];
        d[0] = f2bf(v.x); d[1] = f2bf(v.y); d[2] = f2bf(v.z); d[3] = f2bf(v.w);
    }
    __syncthreads();
    int oc = t >> 4, r4 = (t & 15) * 4;
    #pragma unroll
    for (int i = 0; i < 4; ++i) {
        int orow = oc + i * 16;
        u16 v[4] = {tile[r4][orow], tile[r4 + 1][orow], tile[r4 + 2][orow], tile[r4 + 3][orow]};
        *(uint2*)&out[(size_t)(bx + orow) * R + by + r4] = *(const uint2*)v;
    }
}

// ---------------- bf16 MFMA GEMM, 128x128 tile, BK=32, global_load_lds staging -------
// C = A(MxK) * B(KxN), Bt is N x K row-major.
// MODE 1: bf16 out, (B,H,S,HD) scatter      (Q, K projections)
// MODE 2: fp32 out, row-major M x N         (output projection -> d_out)
// MODE 3: bf16 out, (B,H,HD,S) scatter      (V projection, transposed)
template <int MODE>
__global__ __launch_bounds__(256) void gemm_bt(const u16* __restrict__ A, const u16* __restrict__ Bt,
                                               void* __restrict__ Cout, int M, int N, int K) {
    __shared__ u16 As[128 * 32];
    __shared__ u16 Bs[128 * 32];
    int m0 = blockIdx.y * 128, n0 = blockIdx.x * 128;
    int t = threadIdx.x;
    int wid = t >> 6, lane = t & 63;
    int wr = wid >> 1, wc = wid & 1;
    f32x4v acc[4][4] = {};

    int c0 = wid * 128 + lane;
    int c1 = wid * 128 + 64 + lane;
    const u16* Ar0 = A + (size_t)(m0 + (c0 >> 2)) * K + (c0 & 3) * 8;
    const u16* Ar1 = A + (size_t)(m0 + (c1 >> 2)) * K + (c1 & 3) * 8;
    const u16* Br0 = Bt + (size_t)(n0 + (c0 >> 2)) * K + (c0 & 3) * 8;
    const u16* Br1 = Bt + (size_t)(n0 + (c1 >> 2)) * K + (c1 & 3) * 8;
    u16* Al0 = As + (wid * 128) * 8;
    u16* Al1 = As + (wid * 128 + 64) * 8;
    u16* Bl0 = Bs + (wid * 128) * 8;
    u16* Bl1 = Bs + (wid * 128 + 64) * 8;

    const u16* ap = As + (wr * 64 + (lane & 15)) * 32 + (lane >> 4) * 8;
    const u16* bp = Bs + (wc * 64 + (lane & 15)) * 32 + (lane >> 4) * 8;

    for (int kk = 0; kk < K; kk += 32) {
        gll16(Ar0 + kk, Al0);
        gll16(Ar1 + kk, Al1);
        gll16(Br0 + kk, Bl0);
        gll16(Br1 + kk, Bl1);
        __syncthreads();
        short8 a[4], b[4];
        #pragma unroll
        for (int i = 0; i < 4; ++i) {
            a[i] = *(const short8*)(ap + i * 512);
            b[i] = *(const short8*)(bp + i * 512);
        }
        #pragma unroll
        for (int mf = 0; mf < 4; ++mf)
            #pragma unroll
            for (int nf = 0; nf < 4; ++nf)
                acc[mf][nf] = __builtin_amdgcn_mfma_f32_16x16x32_bf16(a[mf], b[nf], acc[mf][nf], 0, 0, 0);
        __syncthreads();
    }

    int rb = m0 + wr * 64 + ((lane >> 4) << 2);
    int cb = n0 + wc * 64 + (lane & 15);
    #pragma unroll
    for (int mf = 0; mf < 4; ++mf)
        #pragma unroll
        for (int nf = 0; nf < 4; ++nf)
            #pragma unroll
            for (int r = 0; r < 4; ++r) {
                int m = rb + mf * 16 + r;
                int n = cb + nf * 16;
                float v = acc[mf][nf][r];
                if (MODE == 2) {
                    ((float*)Cout)[(size_t)m * N + n] = v;
                } else {
                    int b_ = m >> 11, s = m & (Sc - 1);
                    int h = n >> 7, d = n & (HDc - 1);
                    size_t idx;
                    if (MODE == 1) idx = (((size_t)b_ * Hc + h) * Sc + s) * HDc + d;
                    else           idx = (((size_t)b_ * Hc + h) * HDc + d) * Sc + s;
                    ((u16*)Cout)[idx] = f2bf(v);
                }
            }
}

// ---------------- RoPE in place on bf16 (B,H,S,HD), vectorized (8 dims/thread) ----------------
__global__ __launch_bounds__(256) void rope_k(u16* __restrict__ buf, int nrows) {
    int idx = blockIdx.x * 256 + threadIdx.x;
    int row = idx >> 3, ib = (idx & 7) * 8;
    if (row >= nrows) return;
    int s = row & (Sc - 1);
    u16* p = buf + (size_t)row * HDc + ib;
    uint4 lo = *(const uint4*)p;
    uint4 hi = *(const uint4*)(p + 64);
    u16 lr[8], hr[8];
    const u16* lp = (const u16*)&lo;
    const u16* hp = (const u16*)&hi;
    #pragma unroll
    for (int e = 0; e < 8; ++e) {
        int i = ib + e;
        float freq = exp2f(-(float)i * 0.20762050593045952f); // 10000^(-i/64)
        float ang = (float)s * freq;
        float c, sn;
        sincosf(ang, &sn, &c);
        float x1 = bf2f(lp[e]), x2 = bf2f(hp[e]);
        lr[e] = f2bf(x1 * c - x2 * sn);
        hr[e] = f2bf(x2 * c + x1 * sn);
    }
    *(uint4*)p = *(const uint4*)lr;
    *(uint4*)(p + 64) = *(const uint4*)hr;
}

// ---------------- MFMA flash attention, LDS-staged K/V tiles ----------------
// Q,K bf16 (B,H,S,HD); Vt bf16 (B,H,HD,S); ctx bf16 (B,S,H,HD)
// grid (S/128, B*H), 256 threads; block = 128 q rows, wave = 32 q rows; shared 64-key j-steps.
__global__ __launch_bounds__(256) void fattn_k(const u16* __restrict__ Q, const u16* __restrict__ K,
                                               const u16* __restrict__ Vt, u16* __restrict__ ctx) {
    __shared__ u16 Ks[4][64][32];   // [khalf][key][32k]   16 KB
    __shared__ u16 Vs[2][128][32];  // [khalf][d][32k]     16 KB
    __shared__ u16 Ps[4][32][80];   // per-wave P strip    20 KB
    int t = threadIdx.x, wid = t >> 6, lane = t & 63;
    int bh = blockIdx.y;
    int q0 = blockIdx.x * 128;
    int wrow0 = q0 + wid * 32;
    const u16* Qb = Q + ((size_t)bh * Sc + wrow0) * HDc;
    const u16* Kb = K + (size_t)bh * Sc * HDc;
    const u16* Vb = Vt + (size_t)bh * HDc * Sc;
    int ln = lane & 15, lq = lane >> 4;

    // Q A-frags: A[m=ln][k=lq*8+e]
    short8 aq[2][4];
    #pragma unroll
    for (int mf = 0; mf < 2; ++mf)
        #pragma unroll
        for (int ks = 0; ks < 4; ++ks)
            aq[mf][ks] = *(const short8*)(Qb + (size_t)(mf * 16 + ln) * HDc + ks * 32 + lq * 8);

    f32x4v o[2][8] = {};
    float mr[8], lr[8];
    #pragma unroll
    for (int i = 0; i < 8; ++i) { mr[i] = -1e30f; lr[i] = 0.f; }

    const float sc = 0.08838834764831845f; // 1/sqrt(128)
    int jendw = wrow0 + 31;
    int jendb = q0 + 127;

    for (int j0 = 0; j0 <= jendb; j0 += 64) {
        // ---- stage K tile (64 keys x 128 k) and V^T tile (128 d x 64 keys) ----
        #pragma unroll
        for (int i = 0; i < 4; ++i) {
            int c = (wid * 4 + i) * 64 + lane;
            int ks = c >> 8, row = (c >> 2) & 63, qc = c & 3;
            gll16(Kb + (size_t)(j0 + row) * HDc + ks * 32 + qc * 8,
                  (u16*)Ks + (size_t)(wid * 4 + i) * 512);
        }
        #pragma unroll
        for (int i = 0; i < 4; ++i) {
            int c = (wid * 4 + i) * 64 + lane;
            int ks = c >> 9, row = (c >> 2) & 127, qc = c & 3;
            gll16(Vb + (size_t)row * Sc + j0 + ks * 32 + qc * 8,
                  (u16*)Vs + (size_t)(wid * 4 + i) * 512);
        }
        __syncthreads();

        if (j0 <= jendw) {
            // ---- S = Q K^T ----
            f32x4v sf[2][4] = {};
            #pragma unroll
            for (int ks = 0; ks < 4; ++ks)
                #pragma unroll
                for (int nf = 0; nf < 4; ++nf) {
                    short8 bk = *(const short8*)&Ks[ks][nf * 16 + ln][lq * 8];
                    sf[0][nf] = __builtin_amdgcn_mfma_f32_16x16x32_bf16(aq[0][ks], bk, sf[0][nf], 0, 0, 0);
                    sf[1][nf] = __builtin_amdgcn_mfma_f32_16x16x32_bf16(aq[1][ks], bk, sf[1][nf], 0, 0, 0);
                }

            bool diag = (j0 + 63 > wrow0);
            // ---- online softmax (C layout: row = lq*4+r, col = ln) ----
            #pragma unroll
            for (int mf = 0; mf < 2; ++mf) {
                int rowb = wrow0 + mf * 16 + (lq << 2);
                float sv[4][4];
                #pragma unroll
                for (int nf = 0; nf < 4; ++nf)
                    #pragma unroll
                    for (int r = 0; r < 4; ++r) {
                        float s = sf[mf][nf][r] * sc;
                        if (diag) {
                            int j = j0 + nf * 16 + ln;
                            if (j > rowb + r) s = -1e30f;
                        }
                        sv[nf][r] = s;
                    }
                #pragma unroll
                for (int r = 0; r < 4; ++r) {
                    float mx = fmaxf(fmaxf(sv[0][r], sv[1][r]), fmaxf(sv[2][r], sv[3][r]));
                    #pragma unroll
                    for (int off = 1; off < 16; off <<= 1) mx = fmaxf(mx, __shfl_xor(mx, off, 64));
                    float mo = mr[mf * 4 + r];
                    float mn = fmaxf(mo, mx);
                    float al = __expf(mo - mn);
                    mr[mf * 4 + r] = mn;
                    float ps = 0.f;
                    #pragma unroll
                    for (int nf = 0; nf < 4; ++nf) {
                        float p = __expf(sv[nf][r] - mn);
                        sv[nf][r] = p;
                        ps += p;
                    }
                    #pragma unroll
                    for (int off = 1; off < 16; off <<= 1) ps += __shfl_xor(ps, off, 64);
                    lr[mf * 4 + r] = lr[mf * 4 + r] * al + ps;
                    #pragma unroll
                    for (int nd = 0; nd < 8; ++nd) o[mf][nd][r] *= al;
                }
                #pragma unroll
                for (int nf = 0; nf < 4; ++nf)
                    #pragma unroll
                    for (int r = 0; r < 4; ++r)
                        Ps[wid][mf * 16 + (lq << 2) + r][nf * 16 + ln] = f2bf(sv[nf][r]);
            }

            // ---- O += P V ----
            short8 ap0[2][2];
            #pragma unroll
            for (int mf = 0; mf < 2; ++mf)
                #pragma unroll
                for (int ks = 0; ks < 2; ++ks)
                    ap0[mf][ks] = *(const short8*)&Ps[wid][mf * 16 + ln][ks * 32 + lq * 8];
            #pragma unroll
            for (int ks = 0; ks < 2; ++ks)
                #pragma unroll
                for (int nd = 0; nd < 8; ++nd) {
                    short8 bv = *(const short8*)&Vs[ks][nd * 16 + ln][lq * 8];
                    o[0][nd] = __builtin_amdgcn_mfma_f32_16x16x32_bf16(ap0[0][ks], bv, o[0][nd], 0, 0, 0);
                    o[1][nd] = __builtin_amdgcn_mfma_f32_16x16x32_bf16(ap0[1][ks], bv, o[1][nd], 0, 0, 0);
                }
        }
        __syncthreads();
    }

    // ---- normalize + write ctx (B,S,H,HD) ----
    int b = bh >> 4, h = bh & 15;
    #pragma unroll
    for (int mf = 0; mf < 2; ++mf)
        #pragma unroll
        for (int r = 0; r < 4; ++r) {
            float inv = 1.0f / lr[mf * 4 + r];
            int q = wrow0 + mf * 16 + (lq << 2) + r;
            u16* cp = ctx + (((size_t)(b * Sc + q)) * Hc + h) * HDc + ln;
            #pragma unroll
            for (int nd = 0; nd < 8; ++nd)
                cp[nd * 16] = f2bf(o[mf][nd][r] * inv);
        }
}

extern "C" void kernel_launch(void* const* d_in, const int* in_sizes, int n_in,
                              void* d_out, int out_size, void* d_ws, size_t ws_size,
                              hipStream_t stream) {
    (void)in_sizes; (void)n_in; (void)out_size; (void)ws_size;
    const float* x  = (const float*)d_in[0];
    // d_in[1] = mask: causal, handled analytically
    const float* Wq = (const float*)d_in[2];
    const float* Wk = (const float*)d_in[3];
    const float* Wv = (const float*)d_in[4];
    const float* Wo = (const float*)d_in[5];

    char* w = (char*)d_ws;
    u16* Wt  = (u16*)w; w += (size_t)Dc * Dc * 2;            //  8 MiB, reused 4x
    u16* Qb  = (u16*)w; w += (size_t)Bc * Hc * Sc * HDc * 2; // 16 MiB
    u16* Kb  = (u16*)w; w += (size_t)Bc * Hc * Sc * HDc * 2;
    u16* Vb  = (u16*)w; w += (size_t)Bc * Hc * Sc * HDc * 2; // V^T (B,H,HD,S)
    u16* ctx = (u16*)w; w += (size_t)Bc * Sc * Hc * HDc * 2;
    u16* xb = (u16*)d_out; // bf16 x in d_out scratch (fp32 out = 2x the bytes)

    int nx = Bc * Sc * Dc;
    cvt_k<<<dim3(nx / 2048), 256, 0, stream>>>(x, xb, nx);

    dim3 tgrid(Dc / 64, Dc / 64);
    dim3 ggrid(Dc / 128, (Bc * Sc) / 128);

    tcvt_k<<<tgrid, 256, 0, stream>>>(Wq, Wt, Dc, Dc);
    gemm_bt<1><<<ggrid, 256, 0, stream>>>(xb, Wt, (void*)Qb, Bc * Sc, Dc, Dc);
    tcvt_k<<<tgrid, 256, 0, stream>>>(Wk, Wt, Dc, Dc);
    gemm_bt<1><<<ggrid, 256, 0, stream>>>(xb, Wt, (void*)Kb, Bc * Sc, Dc, Dc);
    tcvt_k<<<tgrid, 256, 0, stream>>>(Wv, Wt, Dc, Dc);
    gemm_bt<3><<<ggrid, 256, 0, stream>>>(xb, Wt, (void*)Vb, Bc * Sc, Dc, Dc);

    int nrows = Bc * Hc * Sc;
    rope_k<<<dim3(nrows * 8 / 256), 256, 0, stream>>>(Qb, nrows);
    rope_k<<<dim3(nrows * 8 / 256), 256, 0, stream>>>(Kb, nrows);

    fattn_k<<<dim3(Sc / 128, Bc * Hc), 256, 0, stream>>>(Qb, Kb, Vb, ctx);

    tcvt_k<<<tgrid, 256, 0, stream>>>(Wo, Wt, Dc, Dc);
    gemm_bt<2><<<ggrid, 256, 0, stream>>>(ctx, Wt, d_out, Bc * Sc, Dc, Dc);
}

// Round 6
// 530.779 us; speedup vs baseline: 4.4305x; 1.1498x over previous
//
#include <hip/hip_runtime.h>

typedef unsigned short u16;
typedef unsigned int u32;

constexpr int Bc = 2, Sc = 2048, Dc = 2048, Hc = 16, HDc = 128;

using short8 = __attribute__((ext_vector_type(8))) short;
using f32x4v = __attribute__((ext_vector_type(4))) float;

static __device__ __forceinline__ float bf2f(u16 v) { return __uint_as_float(((u32)v) << 16); }
static __device__ __forceinline__ u16 f2bf(float f) {
    u32 u = __float_as_uint(f);
    return (u16)((u + 0x7fffu + ((u >> 16) & 1u)) >> 16);
}

// async global->LDS, 16B per lane; LDS dest = wave-uniform base + lane*16
__device__ __forceinline__ void gll16(const u16* g, u16* l) {
    __builtin_amdgcn_global_load_lds((const __attribute__((address_space(1))) void*)g,
                                     (__attribute__((address_space(3))) void*)l, 16, 0, 0);
}

// ---------------- fp32 -> bf16 bulk convert ----------------
__global__ __launch_bounds__(256) void cvt_k(const float* __restrict__ in, u16* __restrict__ out, int n) {
    int i = (blockIdx.x * 256 + threadIdx.x) * 8;
    if (i >= n) return;
    float4 a = *(const float4*)(in + i);
    float4 b = *(const float4*)(in + i + 4);
    u16 r[8] = {f2bf(a.x), f2bf(a.y), f2bf(a.z), f2bf(a.w),
                f2bf(b.x), f2bf(b.y), f2bf(b.z), f2bf(b.w)};
    *(uint4*)(out + i) = *(uint4*)r;
}

// ---------------- fp32 W (R x C) -> bf16 Wt (C x R), 64x64 tiles, vectorized ----------------
__global__ __launch_bounds__(256) void tcvt_k(const float* __restrict__ in, u16* __restrict__ out,
                                              int R, int C) {
    __shared__ u16 tile[64][68];
    int bx = blockIdx.x * 64, by = blockIdx.y * 64;
    int t = threadIdx.x;
    int r = t >> 4, c4 = (t & 15) * 4;
    #pragma unroll
    for (int i = 0; i < 4; ++i) {
        int row = by + r + i * 16;
        float4 v = *(const float4*)(in + (size_t)row * C + bx + c4);
        u16* d = &tile[r + i * 16][c4];
        d[0] = f2bf(v.x); d[1] = f2bf(v.y); d[2] = f2bf(v.z); d[3] = f2bf(v.w);
    }
    __syncthreads();
    int oc = t >> 4, r4 = (t & 15) * 4;
    #pragma unroll
    for (int i = 0; i < 4; ++i) {
        int orow = oc + i * 16;
        u16 v[4] = {tile[r4][orow], tile[r4 + 1][orow], tile[r4 + 2][orow], tile[r4 + 3][orow]};
        *(uint2*)&out[(size_t)(bx + orow) * R + by + r4] = *(const uint2*)v;
    }
}

// ---------------- bf16 MFMA GEMM, 128x128 tile, BK=32, global_load_lds staging -------
// MODE 1: fused QKV epilogue: n<2048 -> Q (B,H,S,HD); <4096 -> K (B,H,S,HD); else V^T (B,H,HD,S)
// MODE 2: fp32 out row-major M x N -> C2
template <int MODE>
__global__ __launch_bounds__(256) void gemm_bt(const u16* __restrict__ A, const u16* __restrict__ Bt,
                                               float* __restrict__ C2, u16* __restrict__ Oq,
                                               u16* __restrict__ Ok, u16* __restrict__ Ov,
                                               int M, int N, int K) {
    __shared__ u16 As[128 * 32];
    __shared__ u16 Bs[128 * 32];
    int m0 = blockIdx.y * 128, n0 = blockIdx.x * 128;
    int t = threadIdx.x;
    int wid = t >> 6, lane = t & 63;
    int wr = wid >> 1, wc = wid & 1;
    f32x4v acc[4][4] = {};

    int c0 = wid * 128 + lane;
    int c1 = wid * 128 + 64 + lane;
    const u16* Ar0 = A + (size_t)(m0 + (c0 >> 2)) * K + (c0 & 3) * 8;
    const u16* Ar1 = A + (size_t)(m0 + (c1 >> 2)) * K + (c1 & 3) * 8;
    const u16* Br0 = Bt + (size_t)(n0 + (c0 >> 2)) * K + (c0 & 3) * 8;
    const u16* Br1 = Bt + (size_t)(n0 + (c1 >> 2)) * K + (c1 & 3) * 8;
    u16* Al0 = As + (wid * 128) * 8;
    u16* Al1 = As + (wid * 128 + 64) * 8;
    u16* Bl0 = Bs + (wid * 128) * 8;
    u16* Bl1 = Bs + (wid * 128 + 64) * 8;

    const u16* ap = As + (wr * 64 + (lane & 15)) * 32 + (lane >> 4) * 8;
    const u16* bp = Bs + (wc * 64 + (lane & 15)) * 32 + (lane >> 4) * 8;

    for (int kk = 0; kk < K; kk += 32) {
        gll16(Ar0 + kk, Al0);
        gll16(Ar1 + kk, Al1);
        gll16(Br0 + kk, Bl0);
        gll16(Br1 + kk, Bl1);
        __syncthreads();
        short8 a[4], b[4];
        #pragma unroll
        for (int i = 0; i < 4; ++i) {
            a[i] = *(const short8*)(ap + i * 512);
            b[i] = *(const short8*)(bp + i * 512);
        }
        #pragma unroll
        for (int mf = 0; mf < 4; ++mf)
            #pragma unroll
            for (int nf = 0; nf < 4; ++nf)
                acc[mf][nf] = __builtin_amdgcn_mfma_f32_16x16x32_bf16(a[mf], b[nf], acc[mf][nf], 0, 0, 0);
        __syncthreads();
    }

    int rb = m0 + wr * 64 + ((lane >> 4) << 2);
    int cb = n0 + wc * 64 + (lane & 15);
    #pragma unroll
    for (int mf = 0; mf < 4; ++mf)
        #pragma unroll
        for (int nf = 0; nf < 4; ++nf)
            #pragma unroll
            for (int r = 0; r < 4; ++r) {
                int m = rb + mf * 16 + r;
                int n = cb + nf * 16;
                float v = acc[mf][nf][r];
                if (MODE == 2) {
                    C2[(size_t)m * N + n] = v;
                } else {
                    int b_ = m >> 11, s = m & (Sc - 1);
                    int which = n >> 11, nn = n & 2047;
                    int h = nn >> 7, d = nn & (HDc - 1);
                    if (which == 2)
                        Ov[(((size_t)b_ * Hc + h) * HDc + d) * Sc + s] = f2bf(v);
                    else {
                        u16* dst = which ? Ok : Oq;
                        dst[(((size_t)b_ * Hc + h) * Sc + s) * HDc + d] = f2bf(v);
                    }
                }
            }
}

// ---------------- RoPE in place on bf16 (B,H,S,HD), vectorized (8 dims/thread) ----------------
__global__ __launch_bounds__(256) void rope_k(u16* __restrict__ buf, int nrows) {
    int idx = blockIdx.x * 256 + threadIdx.x;
    int row = idx >> 3, ib = (idx & 7) * 8;
    if (row >= nrows) return;
    int s = row & (Sc - 1);
    u16* p = buf + (size_t)row * HDc + ib;
    uint4 lo = *(const uint4*)p;
    uint4 hi = *(const uint4*)(p + 64);
    u16 lr[8], hr[8];
    const u16* lp = (const u16*)&lo;
    const u16* hp = (const u16*)&hi;
    #pragma unroll
    for (int e = 0; e < 8; ++e) {
        int i = ib + e;
        float freq = exp2f(-(float)i * 0.20762050593045952f); // 10000^(-i/64)
        float ang = (float)s * freq;
        float c, sn;
        sincosf(ang, &sn, &c);
        float x1 = bf2f(lp[e]), x2 = bf2f(hp[e]);
        lr[e] = f2bf(x1 * c - x2 * sn);
        hr[e] = f2bf(x2 * c + x1 * sn);
    }
    *(uint4*)p = *(const uint4*)lr;
    *(uint4*)(p + 64) = *(const uint4*)hr;
}

// ---------------- MFMA flash attention, fixed-shift softmax, swizzled LDS ----------------
// Q,K bf16 (B,H,S,HD); Vt bf16 (B,H,HD,S); ctx bf16 (B,S,H,HD)
// grid (S/128, B*H), 256 threads; block = 128 q rows, wave = 32 q rows, shared 64-key j-steps.
__global__ __launch_bounds__(256) void fattn_k(const u16* __restrict__ Q, const u16* __restrict__ K,
                                               const u16* __restrict__ Vt, u16* __restrict__ ctx) {
    __shared__ u16 KsA[8192];  // 4 planes x 64 keys x 32 k, chunk-swizzled  16KB
    __shared__ u16 VsA[8192];  // 2 planes x 128 d  x 32 key, chunk-swizzled 16KB
    __shared__ u16 PsA[4 * 32 * 72]; // per-wave P strip, chunk-swizzled     18KB
    int t = threadIdx.x, wid = t >> 6, lane = t & 63;
    int bh = blockIdx.y;
    int q0 = blockIdx.x * 128;
    int wrow0 = q0 + wid * 32;
    const u16* Qb = Q + ((size_t)bh * Sc + wrow0) * HDc;
    const u16* Kb = K + (size_t)bh * Sc * HDc;
    const u16* Vb = Vt + (size_t)bh * HDc * Sc;
    int ln = lane & 15, lq = lane >> 4;
    u16* psw = PsA + wid * 32 * 72;

    // Q A-frags: A[m=ln][k=lq*8+e]
    short8 aq[2][4];
    #pragma unroll
    for (int mf = 0; mf < 2; ++mf)
        #pragma unroll
        for (int ks = 0; ks < 4; ++ks)
            aq[mf][ks] = *(const short8*)(Qb + (size_t)(mf * 16 + ln) * HDc + ks * 32 + lq * 8);

    // ones B-frag (col 0) for the l = rowsum(P) accumulator
    short8 onesb;
    {
        short v = (ln == 0) ? (short)0x3F80 : (short)0;
        #pragma unroll
        for (int e = 0; e < 8; ++e) onesb[e] = v;
    }

    f32x4v o[2][8] = {};
    f32x4v lacc[2] = {};

    const float sc = 0.08838834764831845f; // 1/sqrt(128)
    const float SHIFT = 12.0f;
    int jendw = wrow0 + 31;
    int jendb = q0 + 127;
    int swz = (ln >> 1) & 3; // K/V chunk swizzle for reads

    for (int j0 = 0; j0 <= jendb; j0 += 64) {
        // ---- stage K (64 keys x 128 k) and V^T (128 d x 64 keys), chunk-swizzled ----
        #pragma unroll
        for (int i = 0; i < 4; ++i) {
            int p = (wid * 4 + i) * 64 + lane;
            int plane = p >> 8, key = (p >> 2) & 63;
            int qc = (p & 3) ^ ((key >> 1) & 3);
            gll16(Kb + (size_t)(j0 + key) * HDc + plane * 32 + qc * 8,
                  KsA + (size_t)(wid * 4 + i) * 512);
        }
        #pragma unroll
        for (int i = 0; i < 4; ++i) {
            int p = (wid * 4 + i) * 64 + lane;
            int plane = p >> 9, d = (p >> 2) & 127;
            int qc = (p & 3) ^ ((d >> 1) & 3);
            gll16(Vb + (size_t)d * Sc + j0 + plane * 32 + qc * 8,
                  VsA + (size_t)(wid * 4 + i) * 512);
        }
        __syncthreads();

        if (j0 <= jendw) {
            // ---- S = Q K^T ----
            f32x4v sf[2][4] = {};
            #pragma unroll
            for (int ks = 0; ks < 4; ++ks)
                #pragma unroll
                for (int nf = 0; nf < 4; ++nf) {
                    short8 bk = *(const short8*)(KsA + ks * 2048 + (nf * 16 + ln) * 32 + ((lq ^ swz) << 3));
                    sf[0][nf] = __builtin_amdgcn_mfma_f32_16x16x32_bf16(aq[0][ks], bk, sf[0][nf], 0, 0, 0);
                    sf[1][nf] = __builtin_amdgcn_mfma_f32_16x16x32_bf16(aq[1][ks], bk, sf[1][nf], 0, 0, 0);
                }

            bool diag = (j0 + 63 > wrow0);
            // ---- fixed-shift softmax: p = exp(s*sc - 12); store to P strip ----
            #pragma unroll
            for (int mf = 0; mf < 2; ++mf) {
                int rowb = mf * 16 + (lq << 2);
                #pragma unroll
                for (int nf = 0; nf < 4; ++nf) {
                    int col = nf * 16 + ln;
                    int ck = col >> 3, cl = col & 7;
                    #pragma unroll
                    for (int r = 0; r < 4; ++r) {
                        float p = __expf(fmaf(sf[mf][nf][r], sc, -SHIFT));
                        if (diag && (j0 + col > wrow0 + rowb + r)) p = 0.f;
                        int row = rowb + r;
                        psw[row * 72 + ((ck ^ (row & 7)) << 3) + cl] = f2bf(p);
                    }
                }
            }

            // ---- O += P V ; l += P * ones ----
            short8 ap0[2][2];
            #pragma unroll
            for (int mf = 0; mf < 2; ++mf)
                #pragma unroll
                for (int ks = 0; ks < 2; ++ks)
                    ap0[mf][ks] = *(const short8*)(psw + (mf * 16 + ln) * 72 + (((ks * 4 + lq) ^ (ln & 7)) << 3));
            #pragma unroll
            for (int ks = 0; ks < 2; ++ks) {
                lacc[0] = __builtin_amdgcn_mfma_f32_16x16x32_bf16(ap0[0][ks], onesb, lacc[0], 0, 0, 0);
                lacc[1] = __builtin_amdgcn_mfma_f32_16x16x32_bf16(ap0[1][ks], onesb, lacc[1], 0, 0, 0);
                #pragma unroll
                for (int nd = 0; nd < 8; ++nd) {
                    short8 bv = *(const short8*)(VsA + ks * 4096 + (nd * 16 + ln) * 32 + ((lq ^ swz) << 3));
                    o[0][nd] = __builtin_amdgcn_mfma_f32_16x16x32_bf16(ap0[0][ks], bv, o[0][nd], 0, 0, 0);
                    o[1][nd] = __builtin_amdgcn_mfma_f32_16x16x32_bf16(ap0[1][ks], bv, o[1][nd], 0, 0, 0);
                }
            }
        }
        __syncthreads();
    }

    // ---- normalize + write ctx (B,S,H,HD) ----
    int b = bh >> 4, h = bh & 15;
    #pragma unroll
    for (int mf = 0; mf < 2; ++mf)
        #pragma unroll
        for (int r = 0; r < 4; ++r) {
            float lv = __shfl(lacc[mf][r], lane & 48, 64); // broadcast col-0 lane of this 16-group
            float inv = 1.0f / lv;
            int q = wrow0 + mf * 16 + (lq << 2) + r;
            u16* cp = ctx + (((size_t)(b * Sc + q)) * Hc + h) * HDc + ln;
            #pragma unroll
            for (int nd = 0; nd < 8; ++nd)
                cp[nd * 16] = f2bf(o[mf][nd][r] * inv);
        }
}

extern "C" void kernel_launch(void* const* d_in, const int* in_sizes, int n_in,
                              void* d_out, int out_size, void* d_ws, size_t ws_size,
                              hipStream_t stream) {
    (void)in_sizes; (void)n_in; (void)out_size; (void)ws_size;
    const float* x  = (const float*)d_in[0];
    // d_in[1] = mask: causal, handled analytically
    const float* Wq = (const float*)d_in[2];
    const float* Wk = (const float*)d_in[3];
    const float* Wv = (const float*)d_in[4];
    const float* Wo = (const float*)d_in[5];

    char* w = (char*)d_ws;
    u16* Wt  = (u16*)w; w += (size_t)3 * Dc * Dc * 2;        // 24 MiB (QKV cat; reused for Wo)
    u16* Qb  = (u16*)w; w += (size_t)Bc * Hc * Sc * HDc * 2; // 16 MiB
    u16* Kb  = (u16*)w; w += (size_t)Bc * Hc * Sc * HDc * 2;
    u16* Vb  = (u16*)w; w += (size_t)Bc * Hc * Sc * HDc * 2; // V^T (B,H,HD,S)
    u16* ctx = (u16*)w; w += (size_t)Bc * Sc * Hc * HDc * 2;
    u16* xb = (u16*)d_out; // bf16 x in d_out scratch (fp32 out = 2x the bytes)

    int nx = Bc * Sc * Dc;
    cvt_k<<<dim3(nx / 2048), 256, 0, stream>>>(x, xb, nx);

    dim3 tgrid(Dc / 64, Dc / 64);

    // fused QKV: Wt = [WqT; WkT; WvT] (6144 x 2048)
    tcvt_k<<<tgrid, 256, 0, stream>>>(Wq, Wt, Dc, Dc);
    tcvt_k<<<tgrid, 256, 0, stream>>>(Wk, Wt + (size_t)Dc * Dc, Dc, Dc);
    tcvt_k<<<tgrid, 256, 0, stream>>>(Wv, Wt + (size_t)2 * Dc * Dc, Dc, Dc);
    gemm_bt<1><<<dim3(3 * Dc / 128, (Bc * Sc) / 128), 256, 0, stream>>>(
        xb, Wt, nullptr, Qb, Kb, Vb, Bc * Sc, 3 * Dc, Dc);

    int nrows = Bc * Hc * Sc;
    rope_k<<<dim3(nrows * 8 / 256), 256, 0, stream>>>(Qb, nrows);
    rope_k<<<dim3(nrows * 8 / 256), 256, 0, stream>>>(Kb, nrows);

    fattn_k<<<dim3(Sc / 128, Bc * Hc), 256, 0, stream>>>(Qb, Kb, Vb, ctx);

    tcvt_k<<<tgrid, 256, 0, stream>>>(Wo, Wt, Dc, Dc);
    gemm_bt<2><<<dim3(Dc / 128, (Bc * Sc) / 128), 256, 0, stream>>>(
        ctx, Wt, (float*)d_out, nullptr, nullptr, nullptr, Bc * Sc, Dc, Dc);
}

// Round 7
// 515.352 us; speedup vs baseline: 4.5632x; 1.0299x over previous
//
#include <hip/hip_runtime.h>

typedef unsigned short u16;
typedef unsigned int u32;

constexpr int Bc = 2, Sc = 2048, Dc = 2048, Hc = 16, HDc = 128;

using short8 = __attribute__((ext_vector_type(8))) short;
using f32x4v = __attribute__((ext_vector_type(4))) float;

static __device__ __forceinline__ float bf2f(u16 v) { return __uint_as_float(((u32)v) << 16); }
static __device__ __forceinline__ u16 f2bf(float f) {
    u32 u = __float_as_uint(f);
    return (u16)((u + 0x7fffu + ((u >> 16) & 1u)) >> 16);
}

// async global->LDS, 16B per lane; LDS dest = wave-uniform base + lane*16
__device__ __forceinline__ void gll16(const u16* g, u16* l) {
    __builtin_amdgcn_global_load_lds((const __attribute__((address_space(1))) void*)g,
                                     (__attribute__((address_space(3))) void*)l, 16, 0, 0);
}

// ---------------- fp32 -> bf16 bulk convert ----------------
__global__ __launch_bounds__(256) void cvt_k(const float* __restrict__ in, u16* __restrict__ out, int n) {
    int i = (blockIdx.x * 256 + threadIdx.x) * 8;
    if (i >= n) return;
    float4 a = *(const float4*)(in + i);
    float4 b = *(const float4*)(in + i + 4);
    u16 r[8] = {f2bf(a.x), f2bf(a.y), f2bf(a.z), f2bf(a.w),
                f2bf(b.x), f2bf(b.y), f2bf(b.z), f2bf(b.w)};
    *(uint4*)(out + i) = *(uint4*)r;
}

// ---------------- fp32 W (R x C) -> bf16 Wt (C x R), 64x64 tiles, vectorized ----------------
__global__ __launch_bounds__(256) void tcvt_k(const float* __restrict__ in, u16* __restrict__ out,
                                              int R, int C) {
    __shared__ u16 tile[64][68];
    int bx = blockIdx.x * 64, by = blockIdx.y * 64;
    int t = threadIdx.x;
    int r = t >> 4, c4 = (t & 15) * 4;
    #pragma unroll
    for (int i = 0; i < 4; ++i) {
        int row = by + r + i * 16;
        float4 v = *(const float4*)(in + (size_t)row * C + bx + c4);
        u16* d = &tile[r + i * 16][c4];
        d[0] = f2bf(v.x); d[1] = f2bf(v.y); d[2] = f2bf(v.z); d[3] = f2bf(v.w);
    }
    __syncthreads();
    int oc = t >> 4, r4 = (t & 15) * 4;
    #pragma unroll
    for (int i = 0; i < 4; ++i) {
        int orow = oc + i * 16;
        u16 v[4] = {tile[r4][orow], tile[r4 + 1][orow], tile[r4 + 2][orow], tile[r4 + 3][orow]};
        *(uint2*)&out[(size_t)(bx + orow) * R + by + r4] = *(const uint2*)v;
    }
}

// ---------------- bf16 MFMA GEMM, 128x128 tile, BK=32, swizzled LDS, coalesced epilogue ----
// MODE 1: fused QKV epilogue: n<2048 -> Q (B,H,S,HD) +RoPE; <4096 -> K +RoPE; else V^T (B,H,HD,S)
// MODE 2: fp32 out row-major M x N -> C2
template <int MODE>
__global__ __launch_bounds__(256) void gemm_bt(const u16* __restrict__ A, const u16* __restrict__ Bt,
                                               float* __restrict__ C2, u16* __restrict__ Oq,
                                               u16* __restrict__ Ok, u16* __restrict__ Ov,
                                               int M, int N, int K) {
    __shared__ u16 SM[(MODE == 1) ? 16640 : 8192]; // staging 16KB; MODE1 epilogue strip 33KB
    u16* As = SM;
    u16* Bs = SM + 4096;
    int m0 = blockIdx.y * 128, n0 = blockIdx.x * 128;
    int t = threadIdx.x;
    int wid = t >> 6, lane = t & 63;
    int wr = wid >> 1, wc = wid & 1;
    f32x4v acc[4][4] = {};

    // staging: chunk c -> row c>>2, stored chunk c&3 holds global chunk (c&3)^((c>>3)&3)
    int c0 = wid * 128 + lane;
    int c1 = wid * 128 + 64 + lane;
    const u16* Ar0 = A + (size_t)(m0 + (c0 >> 2)) * K + (((c0 & 3) ^ ((c0 >> 3) & 3)) * 8);
    const u16* Ar1 = A + (size_t)(m0 + (c1 >> 2)) * K + (((c1 & 3) ^ ((c1 >> 3) & 3)) * 8);
    const u16* Br0 = Bt + (size_t)(n0 + (c0 >> 2)) * K + (((c0 & 3) ^ ((c0 >> 3) & 3)) * 8);
    const u16* Br1 = Bt + (size_t)(n0 + (c1 >> 2)) * K + (((c1 & 3) ^ ((c1 >> 3) & 3)) * 8);
    u16* Al0 = As + (size_t)c0 * 8 - (size_t)(lane * 8) + lane * 8; // = As + c0*8 (wave-uniform base + lane*16B)
    u16* Al1 = As + (size_t)(wid * 128 + 64) * 8;
    u16* Bl0 = Bs + (size_t)(wid * 128) * 8;
    u16* Bl1 = Bs + (size_t)(wid * 128 + 64) * 8;
    Al0 = As + (size_t)(wid * 128) * 8;

    int sw = (lane >> 1) & 3; // = ((row&15)>>1)&3 for row=lane&15
    const u16* ap = As + (wr * 64 + (lane & 15)) * 32 + ((((lane >> 4)) ^ sw) << 3);
    const u16* bp = Bs + (wc * 64 + (lane & 15)) * 32 + ((((lane >> 4)) ^ sw) << 3);

    for (int kk = 0; kk < K; kk += 32) {
        gll16(Ar0 + kk, Al0);
        gll16(Ar1 + kk, Al1);
        gll16(Br0 + kk, Bl0);
        gll16(Br1 + kk, Bl1);
        __syncthreads();
        short8 a[4], b[4];
        #pragma unroll
        for (int i = 0; i < 4; ++i) {
            a[i] = *(const short8*)(ap + i * 512);
            b[i] = *(const short8*)(bp + i * 512);
        }
        #pragma unroll
        for (int mf = 0; mf < 4; ++mf)
            #pragma unroll
            for (int nf = 0; nf < 4; ++nf)
                acc[mf][nf] = __builtin_amdgcn_mfma_f32_16x16x32_bf16(a[mf], b[nf], acc[mf][nf], 0, 0, 0);
        __syncthreads();
    }

    int ln = lane & 15, lq = lane >> 4;
    if (MODE == 2) {
        int rb = m0 + wr * 64 + (lq << 2);
        int cb = n0 + wc * 64 + ln;
        #pragma unroll
        for (int mf = 0; mf < 4; ++mf)
            #pragma unroll
            for (int nf = 0; nf < 4; ++nf)
                #pragma unroll
                for (int r = 0; r < 4; ++r)
                    C2[(size_t)(rb + mf * 16 + r) * N + cb + nf * 16] = acc[mf][nf][r];
        return;
    }

    // ---- MODE 1: stage tile to LDS (bf16, stride 130), then coalesced writes ----
    u16* Es = SM;
    {
        int rl0 = wr * 64 + (lq << 2), cl0 = wc * 64 + ln;
        #pragma unroll
        for (int mf = 0; mf < 4; ++mf)
            #pragma unroll
            for (int nf = 0; nf < 4; ++nf)
                #pragma unroll
                for (int r = 0; r < 4; ++r)
                    Es[(rl0 + mf * 16 + r) * 130 + cl0 + nf * 16] = f2bf(acc[mf][nf][r]);
    }
    __syncthreads();

    int which = n0 >> 11;
    int h = (n0 & 2047) >> 7;
    int b_ = m0 >> 11;
    int s0 = m0 & (Sc - 1);

    if (which < 2) {
        // Q or K: +RoPE. thread t: row r=t>>1, half h2=t&1; writes 128B contiguous.
        u16* dst0 = which ? Ok : Oq;
        int r = t >> 1, h2 = t & 1;
        int s = s0 + r;
        const u16* row = Es + r * 130;
        u16* dp = dst0 + (((size_t)(b_ * Hc + h)) * Sc + s) * HDc + h2 * 64;
        #pragma unroll
        for (int j8 = 0; j8 < 64; j8 += 8) {
            uint4 aa = *(const uint4*)(row + j8);
            uint4 bb = *(const uint4*)(row + 64 + j8);
            const u16* ap8 = (const u16*)&aa;
            const u16* bp8 = (const u16*)&bb;
            u16 ov[8];
            #pragma unroll
            for (int e = 0; e < 8; ++e) {
                float freq = exp2f(-(float)(j8 + e) * 0.20762050593045952f); // 10000^(-j/64)
                float ang = (float)s * freq;
                float c, sn;
                sincosf(ang, &sn, &c);
                float x1 = bf2f(ap8[e]), x2 = bf2f(bp8[e]);
                ov[e] = h2 ? f2bf(x2 * c + x1 * sn) : f2bf(x1 * c - x2 * sn);
            }
            *(uint4*)(dp + j8) = *(const uint4*)ov;
        }
    } else {
        // V^T: thread t: col d=t>>1, row-half sh=t&1; transpose via LDS, 128B contiguous stores.
        int d = t >> 1, sh = t & 1;
        u16* dp = Ov + (((size_t)(b_ * Hc + h)) * HDc + d) * Sc + s0 + sh * 64;
        #pragma unroll
        for (int r8 = 0; r8 < 64; r8 += 8) {
            u16 ov[8];
            #pragma unroll
            for (int e = 0; e < 8; ++e)
                ov[e] = Es[(sh * 64 + r8 + e) * 130 + d];
            *(uint4*)(dp + r8) = *(const uint4*)ov;
        }
    }
}

// ---------------- MFMA flash attention, fixed-shift softmax, swizzled LDS ----------------
// Q,K bf16 (B,H,S,HD); Vt bf16 (B,H,HD,S); ctx bf16 (B,S,H,HD)
// grid (S/128, B*H), 256 threads; block = 128 q rows, wave = 32 q rows, shared 64-key j-steps.
__global__ __launch_bounds__(256) void fattn_k(const u16* __restrict__ Q, const u16* __restrict__ K,
                                               const u16* __restrict__ Vt, u16* __restrict__ ctx) {
    __shared__ u16 KsA[8192];  // 4 planes x 64 keys x 32 k, chunk-swizzled  16KB
    __shared__ u16 VsA[8192];  // 2 planes x 128 d  x 32 key, chunk-swizzled 16KB
    __shared__ u16 PsA[4 * 32 * 72]; // per-wave P strip, chunk-swizzled     18KB
    int t = threadIdx.x, wid = t >> 6, lane = t & 63;
    int bh = blockIdx.y;
    int q0 = blockIdx.x * 128;
    int wrow0 = q0 + wid * 32;
    const u16* Qb = Q + ((size_t)bh * Sc + wrow0) * HDc;
    const u16* Kb = K + (size_t)bh * Sc * HDc;
    const u16* Vb = Vt + (size_t)bh * HDc * Sc;
    int ln = lane & 15, lq = lane >> 4;
    u16* psw = PsA + wid * 32 * 72;

    // Q A-frags: A[m=ln][k=lq*8+e]
    short8 aq[2][4];
    #pragma unroll
    for (int mf = 0; mf < 2; ++mf)
        #pragma unroll
        for (int ks = 0; ks < 4; ++ks)
            aq[mf][ks] = *(const short8*)(Qb + (size_t)(mf * 16 + ln) * HDc + ks * 32 + lq * 8);

    // ones B-frag (col 0) for the l = rowsum(P) accumulator
    short8 onesb;
    {
        short v = (ln == 0) ? (short)0x3F80 : (short)0;
        #pragma unroll
        for (int e = 0; e < 8; ++e) onesb[e] = v;
    }

    f32x4v o[2][8] = {};
    f32x4v lacc[2] = {};

    const float sc = 0.08838834764831845f; // 1/sqrt(128)
    const float SHIFT = 12.0f;
    int jendw = wrow0 + 31;
    int jendb = q0 + 127;
    int swz = (ln >> 1) & 3; // K/V chunk swizzle for reads

    for (int j0 = 0; j0 <= jendb; j0 += 64) {
        // ---- stage K (64 keys x 128 k) and V^T (128 d x 64 keys), chunk-swizzled ----
        #pragma unroll
        for (int i = 0; i < 4; ++i) {
            int p = (wid * 4 + i) * 64 + lane;
            int plane = p >> 8, key = (p >> 2) & 63;
            int qc = (p & 3) ^ ((key >> 1) & 3);
            gll16(Kb + (size_t)(j0 + key) * HDc + plane * 32 + qc * 8,
                  KsA + (size_t)(wid * 4 + i) * 512);
        }
        #pragma unroll
        for (int i = 0; i < 4; ++i) {
            int p = (wid * 4 + i) * 64 + lane;
            int plane = p >> 9, d = (p >> 2) & 127;
            int qc = (p & 3) ^ ((d >> 1) & 3);
            gll16(Vb + (size_t)d * Sc + j0 + plane * 32 + qc * 8,
                  VsA + (size_t)(wid * 4 + i) * 512);
        }
        __syncthreads();

        if (j0 <= jendw) {
            // ---- S = Q K^T ----
            f32x4v sf[2][4] = {};
            #pragma unroll
            for (int ks = 0; ks < 4; ++ks)
                #pragma unroll
                for (int nf = 0; nf < 4; ++nf) {
                    short8 bk = *(const short8*)(KsA + ks * 2048 + (nf * 16 + ln) * 32 + ((lq ^ swz) << 3));
                    sf[0][nf] = __builtin_amdgcn_mfma_f32_16x16x32_bf16(aq[0][ks], bk, sf[0][nf], 0, 0, 0);
                    sf[1][nf] = __builtin_amdgcn_mfma_f32_16x16x32_bf16(aq[1][ks], bk, sf[1][nf], 0, 0, 0);
                }

            bool diag = (j0 + 63 > wrow0);
            // ---- fixed-shift softmax: p = exp(s*sc - 12); store to P strip ----
            #pragma unroll
            for (int mf = 0; mf < 2; ++mf) {
                int rowb = mf * 16 + (lq << 2);
                #pragma unroll
                for (int nf = 0; nf < 4; ++nf) {
                    int col = nf * 16 + ln;
                    int ck = col >> 3, cl = col & 7;
                    #pragma unroll
                    for (int r = 0; r < 4; ++r) {
                        float p = __expf(fmaf(sf[mf][nf][r], sc, -SHIFT));
                        if (diag && (j0 + col > wrow0 + rowb + r)) p = 0.f;
                        int row = rowb + r;
                        psw[row * 72 + ((ck ^ (row & 7)) << 3) + cl] = f2bf(p);
                    }
                }
            }

            // ---- O += P V ; l += P * ones ----
            short8 ap0[2][2];
            #pragma unroll
            for (int mf = 0; mf < 2; ++mf)
                #pragma unroll
                for (int ks = 0; ks < 2; ++ks)
                    ap0[mf][ks] = *(const short8*)(psw + (mf * 16 + ln) * 72 + (((ks * 4 + lq) ^ (ln & 7)) << 3));
            #pragma unroll
            for (int ks = 0; ks < 2; ++ks) {
                lacc[0] = __builtin_amdgcn_mfma_f32_16x16x32_bf16(ap0[0][ks], onesb, lacc[0], 0, 0, 0);
                lacc[1] = __builtin_amdgcn_mfma_f32_16x16x32_bf16(ap0[1][ks], onesb, lacc[1], 0, 0, 0);
                #pragma unroll
                for (int nd = 0; nd < 8; ++nd) {
                    short8 bv = *(const short8*)(VsA + ks * 4096 + (nd * 16 + ln) * 32 + ((lq ^ swz) << 3));
                    o[0][nd] = __builtin_amdgcn_mfma_f32_16x16x32_bf16(ap0[0][ks], bv, o[0][nd], 0, 0, 0);
                    o[1][nd] = __builtin_amdgcn_mfma_f32_16x16x32_bf16(ap0[1][ks], bv, o[1][nd], 0, 0, 0);
                }
            }
        }
        __syncthreads();
    }

    // ---- normalize + write ctx (B,S,H,HD) ----
    int b = bh >> 4, h = bh & 15;
    #pragma unroll
    for (int mf = 0; mf < 2; ++mf)
        #pragma unroll
        for (int r = 0; r < 4; ++r) {
            float lv = __shfl(lacc[mf][r], lane & 48, 64); // broadcast col-0 lane of this 16-group
            float inv = 1.0f / lv;
            int q = wrow0 + mf * 16 + (lq << 2) + r;
            u16* cp = ctx + (((size_t)(b * Sc + q)) * Hc + h) * HDc + ln;
            #pragma unroll
            for (int nd = 0; nd < 8; ++nd)
                cp[nd * 16] = f2bf(o[mf][nd][r] * inv);
        }
}

extern "C" void kernel_launch(void* const* d_in, const int* in_sizes, int n_in,
                              void* d_out, int out_size, void* d_ws, size_t ws_size,
                              hipStream_t stream) {
    (void)in_sizes; (void)n_in; (void)out_size; (void)ws_size;
    const float* x  = (const float*)d_in[0];
    // d_in[1] = mask: causal, handled analytically
    const float* Wq = (const float*)d_in[2];
    const float* Wk = (const float*)d_in[3];
    const float* Wv = (const float*)d_in[4];
    const float* Wo = (const float*)d_in[5];

    char* w = (char*)d_ws;
    u16* Wt  = (u16*)w; w += (size_t)3 * Dc * Dc * 2;        // 24 MiB (QKV cat; reused for Wo)
    u16* Qb  = (u16*)w; w += (size_t)Bc * Hc * Sc * HDc * 2; // 16 MiB
    u16* Kb  = (u16*)w; w += (size_t)Bc * Hc * Sc * HDc * 2;
    u16* Vb  = (u16*)w; w += (size_t)Bc * Hc * Sc * HDc * 2; // V^T (B,H,HD,S)
    u16* ctx = (u16*)w; w += (size_t)Bc * Sc * Hc * HDc * 2;
    u16* xb = (u16*)d_out; // bf16 x in d_out scratch (fp32 out = 2x the bytes)

    int nx = Bc * Sc * Dc;
    cvt_k<<<dim3(nx / 2048), 256, 0, stream>>>(x, xb, nx);

    dim3 tgrid(Dc / 64, Dc / 64);

    // fused QKV: Wt = [WqT; WkT; WvT] (6144 x 2048)
    tcvt_k<<<tgrid, 256, 0, stream>>>(Wq, Wt, Dc, Dc);
    tcvt_k<<<tgrid, 256, 0, stream>>>(Wk, Wt + (size_t)Dc * Dc, Dc, Dc);
    tcvt_k<<<tgrid, 256, 0, stream>>>(Wv, Wt + (size_t)2 * Dc * Dc, Dc, Dc);
    gemm_bt<1><<<dim3(3 * Dc / 128, (Bc * Sc) / 128), 256, 0, stream>>>(
        xb, Wt, nullptr, Qb, Kb, Vb, Bc * Sc, 3 * Dc, Dc);

    fattn_k<<<dim3(Sc / 128, Bc * Hc), 256, 0, stream>>>(Qb, Kb, Vb, ctx);

    tcvt_k<<<tgrid, 256, 0, stream>>>(Wo, Wt, Dc, Dc);
    gemm_bt<2><<<dim3(Dc / 128, (Bc * Sc) / 128), 256, 0, stream>>>(
        ctx, Wt, (float*)d_out, nullptr, nullptr, nullptr, Bc * Sc, Dc, Dc);
}

// Round 8
// 427.782 us; speedup vs baseline: 5.4973x; 1.2047x over previous
//
#include <hip/hip_runtime.h>

typedef unsigned short u16;
typedef unsigned int u32;

constexpr int Bc = 2, Sc = 2048, Dc = 2048, Hc = 16, HDc = 128;

using short8 = __attribute__((ext_vector_type(8))) short;
using f32x4v = __attribute__((ext_vector_type(4))) float;

static __device__ __forceinline__ float bf2f(u16 v) { return __uint_as_float(((u32)v) << 16); }
static __device__ __forceinline__ u16 f2bf(float f) {
    u32 u = __float_as_uint(f);
    return (u16)((u + 0x7fffu + ((u >> 16) & 1u)) >> 16);
}

// async global->LDS, 16B per lane; LDS dest = wave-uniform base + lane*16
__device__ __forceinline__ void gll16(const u16* g, u16* l) {
    __builtin_amdgcn_global_load_lds((const __attribute__((address_space(1))) void*)g,
                                     (__attribute__((address_space(3))) void*)l, 16, 0, 0);
}

// ---------------- RoPE cos/sin tables: [S][64] fp32 ----------------
__global__ __launch_bounds__(256) void rope_tab_k(float* __restrict__ ctab, float* __restrict__ stab) {
    int idx = blockIdx.x * 256 + threadIdx.x; // S*64 threads
    int s = idx >> 6, i = idx & 63;
    float freq = exp2f(-(float)i * 0.20762050593045952f); // 10000^(-i/64)
    float ang = (float)s * freq;
    float c, sn;
    sincosf(ang, &sn, &c);
    ctab[idx] = c;
    stab[idx] = sn;
}

// ---------------- fp32 -> bf16 bulk convert ----------------
__global__ __launch_bounds__(256) void cvt_k(const float* __restrict__ in, u16* __restrict__ out, int n) {
    int i = (blockIdx.x * 256 + threadIdx.x) * 8;
    if (i >= n) return;
    float4 a = *(const float4*)(in + i);
    float4 b = *(const float4*)(in + i + 4);
    u16 r[8] = {f2bf(a.x), f2bf(a.y), f2bf(a.z), f2bf(a.w),
                f2bf(b.x), f2bf(b.y), f2bf(b.z), f2bf(b.w)};
    *(uint4*)(out + i) = *(uint4*)r;
}

// ---------------- fp32 W (R x C) -> bf16 Wt (C x R), 64x64 tiles; z selects source ----------------
__global__ __launch_bounds__(256) void tcvt3_k(const float* __restrict__ in0, const float* __restrict__ in1,
                                               const float* __restrict__ in2, u16* __restrict__ out,
                                               int R, int C) {
    __shared__ u16 tile[64][68];
    const float* in = (blockIdx.z == 0) ? in0 : (blockIdx.z == 1) ? in1 : in2;
    u16* o = out + (size_t)blockIdx.z * R * C;
    int bx = blockIdx.x * 64, by = blockIdx.y * 64;
    int t = threadIdx.x;
    int r = t >> 4, c4 = (t & 15) * 4;
    #pragma unroll
    for (int i = 0; i < 4; ++i) {
        int row = by + r + i * 16;
        float4 v = *(const float4*)(in + (size_t)row * C + bx + c4);
        u16* d = &tile[r + i * 16][c4];
        d[0] = f2bf(v.x); d[1] = f2bf(v.y); d[2] = f2bf(v.z); d[3] = f2bf(v.w);
    }
    __syncthreads();
    int oc = t >> 4, r4 = (t & 15) * 4;
    #pragma unroll
    for (int i = 0; i < 4; ++i) {
        int orow = oc + i * 16;
        u16 v[4] = {tile[r4][orow], tile[r4 + 1][orow], tile[r4 + 2][orow], tile[r4 + 3][orow]};
        *(uint2*)&o[(size_t)(bx + orow) * R + by + r4] = *(const uint2*)v;
    }
}

// ---------------- bf16 MFMA GEMM, 128x128 tile, BK=32, swizzled LDS, coalesced epilogue ----
// MODE 1: fused QKV epilogue: n<2048 -> Q (B,H,S,HD) +RoPE; <4096 -> K +RoPE; else V^T (B,H,HD,S)
// MODE 2: fp32 out row-major M x N -> C2
template <int MODE>
__global__ __launch_bounds__(256) void gemm_bt(const u16* __restrict__ A, const u16* __restrict__ Bt,
                                               float* __restrict__ C2, u16* __restrict__ Oq,
                                               u16* __restrict__ Ok, u16* __restrict__ Ov,
                                               const float* __restrict__ ctab,
                                               const float* __restrict__ stab,
                                               int M, int N, int K) {
    __shared__ u16 SM[(MODE == 1) ? 16640 : 8192]; // staging 16KB; MODE1 epilogue strip 33KB
    u16* As = SM;
    u16* Bs = SM + 4096;
    int m0 = blockIdx.y * 128, n0 = blockIdx.x * 128;
    int t = threadIdx.x;
    int wid = t >> 6, lane = t & 63;
    int wr = wid >> 1, wc = wid & 1;
    f32x4v acc[4][4] = {};

    // staging: chunk c -> row c>>2, stored chunk c&3 holds global chunk (c&3)^((c>>3)&3)
    int c0 = wid * 128 + lane;
    int c1 = wid * 128 + 64 + lane;
    const u16* Ar0 = A + (size_t)(m0 + (c0 >> 2)) * K + (((c0 & 3) ^ ((c0 >> 3) & 3)) * 8);
    const u16* Ar1 = A + (size_t)(m0 + (c1 >> 2)) * K + (((c1 & 3) ^ ((c1 >> 3) & 3)) * 8);
    const u16* Br0 = Bt + (size_t)(n0 + (c0 >> 2)) * K + (((c0 & 3) ^ ((c0 >> 3) & 3)) * 8);
    const u16* Br1 = Bt + (size_t)(n0 + (c1 >> 2)) * K + (((c1 & 3) ^ ((c1 >> 3) & 3)) * 8);
    u16* Al0 = As + (size_t)(wid * 128) * 8;
    u16* Al1 = As + (size_t)(wid * 128 + 64) * 8;
    u16* Bl0 = Bs + (size_t)(wid * 128) * 8;
    u16* Bl1 = Bs + (size_t)(wid * 128 + 64) * 8;

    int sw = (lane >> 1) & 3; // = ((row&15)>>1)&3 for row=lane&15
    const u16* ap = As + (wr * 64 + (lane & 15)) * 32 + ((((lane >> 4)) ^ sw) << 3);
    const u16* bp = Bs + (wc * 64 + (lane & 15)) * 32 + ((((lane >> 4)) ^ sw) << 3);

    for (int kk = 0; kk < K; kk += 32) {
        gll16(Ar0 + kk, Al0);
        gll16(Ar1 + kk, Al1);
        gll16(Br0 + kk, Bl0);
        gll16(Br1 + kk, Bl1);
        __syncthreads();
        short8 a[4], b[4];
        #pragma unroll
        for (int i = 0; i < 4; ++i) {
            a[i] = *(const short8*)(ap + i * 512);
            b[i] = *(const short8*)(bp + i * 512);
        }
        #pragma unroll
        for (int mf = 0; mf < 4; ++mf)
            #pragma unroll
            for (int nf = 0; nf < 4; ++nf)
                acc[mf][nf] = __builtin_amdgcn_mfma_f32_16x16x32_bf16(a[mf], b[nf], acc[mf][nf], 0, 0, 0);
        __syncthreads();
    }

    int ln = lane & 15, lq = lane >> 4;
    if (MODE == 2) {
        int rb = m0 + wr * 64 + (lq << 2);
        int cb = n0 + wc * 64 + ln;
        #pragma unroll
        for (int mf = 0; mf < 4; ++mf)
            #pragma unroll
            for (int nf = 0; nf < 4; ++nf)
                #pragma unroll
                for (int r = 0; r < 4; ++r)
                    C2[(size_t)(rb + mf * 16 + r) * N + cb + nf * 16] = acc[mf][nf][r];
        return;
    }

    // ---- MODE 1: stage tile to LDS (bf16, stride 130), then coalesced writes ----
    u16* Es = SM;
    {
        int rl0 = wr * 64 + (lq << 2), cl0 = wc * 64 + ln;
        #pragma unroll
        for (int mf = 0; mf < 4; ++mf)
            #pragma unroll
            for (int nf = 0; nf < 4; ++nf)
                #pragma unroll
                for (int r = 0; r < 4; ++r)
                    Es[(rl0 + mf * 16 + r) * 130 + cl0 + nf * 16] = f2bf(acc[mf][nf][r]);
    }
    __syncthreads();

    int which = n0 >> 11;
    int h = (n0 & 2047) >> 7;
    int b_ = m0 >> 11;
    int s0 = m0 & (Sc - 1);

    if (which < 2) {
        // Q or K: +RoPE from tables. thread t: row r=t>>1, half h2=t&1; writes 128B contiguous.
        u16* dst0 = which ? Ok : Oq;
        int r = t >> 1, h2 = t & 1;
        int s = s0 + r;
        const u16* row = Es + r * 130;
        const float* ct = ctab + (size_t)s * 64;
        const float* st = stab + (size_t)s * 64;
        u16* dp = dst0 + (((size_t)(b_ * Hc + h)) * Sc + s) * HDc + h2 * 64;
        #pragma unroll
        for (int j8 = 0; j8 < 64; j8 += 8) {
            uint4 aa = *(const uint4*)(row + j8);
            uint4 bb = *(const uint4*)(row + 64 + j8);
            const u16* ap8 = (const u16*)&aa;
            const u16* bp8 = (const u16*)&bb;
            float4 c0 = *(const float4*)(ct + j8);
            float4 c1 = *(const float4*)(ct + j8 + 4);
            float4 sn0 = *(const float4*)(st + j8);
            float4 sn1 = *(const float4*)(st + j8 + 4);
            const float* cf = (const float*)&c0; // c0,c1 contiguous on stack
            float cc[8] = {c0.x, c0.y, c0.z, c0.w, c1.x, c1.y, c1.z, c1.w};
            float ss[8] = {sn0.x, sn0.y, sn0.z, sn0.w, sn1.x, sn1.y, sn1.z, sn1.w};
            (void)cf;
            u16 ov[8];
            #pragma unroll
            for (int e = 0; e < 8; ++e) {
                float x1 = bf2f(ap8[e]), x2 = bf2f(bp8[e]);
                ov[e] = h2 ? f2bf(x2 * cc[e] + x1 * ss[e]) : f2bf(x1 * cc[e] - x2 * ss[e]);
            }
            *(uint4*)(dp + j8) = *(const uint4*)ov;
        }
    } else {
        // V^T: thread t: col d=t>>1, row-half sh=t&1; transpose via LDS, 128B contiguous stores.
        int d = t >> 1, sh = t & 1;
        u16* dp = Ov + (((size_t)(b_ * Hc + h)) * HDc + d) * Sc + s0 + sh * 64;
        #pragma unroll
        for (int r8 = 0; r8 < 64; r8 += 8) {
            u16 ov[8];
            #pragma unroll
            for (int e = 0; e < 8; ++e)
                ov[e] = Es[(sh * 64 + r8 + e) * 130 + d];
            *(uint4*)(dp + r8) = *(const uint4*)ov;
        }
    }
}

// ---------------- MFMA flash attention, fixed-shift softmax, swizzled LDS ----------------
// Q,K bf16 (B,H,S,HD); Vt bf16 (B,H,HD,S); ctx bf16 (B,S,H,HD)
// grid (B*H, 16): x=bh (same-bh blocks stride-32 apart -> same XCD under round-robin),
// y -> qtile = y<8 ? y : 23-y (CU block-pairs sum to constant work under round-robin).
__global__ __launch_bounds__(256) void fattn_k(const u16* __restrict__ Q, const u16* __restrict__ K,
                                               const u16* __restrict__ Vt, u16* __restrict__ ctx) {
    __shared__ u16 KsA[8192];  // 4 planes x 64 keys x 32 k, chunk-swizzled  16KB
    __shared__ u16 VsA[8192];  // 2 planes x 128 d  x 32 key, chunk-swizzled 16KB
    __shared__ u16 PsA[4 * 32 * 72]; // per-wave P strip, chunk-swizzled     18KB
    int t = threadIdx.x, wid = t >> 6, lane = t & 63;
    int bh = blockIdx.x;
    int yt = blockIdx.y;
    int qi = (yt < 8) ? yt : 23 - yt;
    int q0 = qi << 7;
    int wrow0 = q0 + wid * 32;
    const u16* Qb = Q + ((size_t)bh * Sc + wrow0) * HDc;
    const u16* Kb = K + (size_t)bh * Sc * HDc;
    const u16* Vb = Vt + (size_t)bh * HDc * Sc;
    int ln = lane & 15, lq = lane >> 4;
    u16* psw = PsA + wid * 32 * 72;

    // Q A-frags: A[m=ln][k=lq*8+e]
    short8 aq[2][4];
    #pragma unroll
    for (int mf = 0; mf < 2; ++mf)
        #pragma unroll
        for (int ks = 0; ks < 4; ++ks)
            aq[mf][ks] = *(const short8*)(Qb + (size_t)(mf * 16 + ln) * HDc + ks * 32 + lq * 8);

    // ones B-frag (col 0) for the l = rowsum(P) accumulator
    short8 onesb;
    {
        short v = (ln == 0) ? (short)0x3F80 : (short)0;
        #pragma unroll
        for (int e = 0; e < 8; ++e) onesb[e] = v;
    }

    f32x4v o[2][8] = {};
    f32x4v lacc[2] = {};

    const float sc = 0.08838834764831845f; // 1/sqrt(128)
    const float SHIFT = 12.0f;
    int jendw = wrow0 + 31;
    int jendb = q0 + 127;
    int swz = (ln >> 1) & 3; // K/V chunk swizzle for reads

    for (int j0 = 0; j0 <= jendb; j0 += 64) {
        // ---- stage K (64 keys x 128 k) and V^T (128 d x 64 keys), chunk-swizzled ----
        #pragma unroll
        for (int i = 0; i < 4; ++i) {
            int p = (wid * 4 + i) * 64 + lane;
            int plane = p >> 8, key = (p >> 2) & 63;
            int qc = (p & 3) ^ ((key >> 1) & 3);
            gll16(Kb + (size_t)(j0 + key) * HDc + plane * 32 + qc * 8,
                  KsA + (size_t)(wid * 4 + i) * 512);
        }
        #pragma unroll
        for (int i = 0; i < 4; ++i) {
            int p = (wid * 4 + i) * 64 + lane;
            int plane = p >> 9, d = (p >> 2) & 127;
            int qc = (p & 3) ^ ((d >> 1) & 3);
            gll16(Vb + (size_t)d * Sc + j0 + plane * 32 + qc * 8,
                  VsA + (size_t)(wid * 4 + i) * 512);
        }
        __syncthreads();

        if (j0 <= jendw) {
            // ---- S = Q K^T ----
            f32x4v sf[2][4] = {};
            #pragma unroll
            for (int ks = 0; ks < 4; ++ks)
                #pragma unroll
                for (int nf = 0; nf < 4; ++nf) {
                    short8 bk = *(const short8*)(KsA + ks * 2048 + (nf * 16 + ln) * 32 + ((lq ^ swz) << 3));
                    sf[0][nf] = __builtin_amdgcn_mfma_f32_16x16x32_bf16(aq[0][ks], bk, sf[0][nf], 0, 0, 0);
                    sf[1][nf] = __builtin_amdgcn_mfma_f32_16x16x32_bf16(aq[1][ks], bk, sf[1][nf], 0, 0, 0);
                }

            bool diag = (j0 + 63 > wrow0);
            // ---- fixed-shift softmax: p = exp(s*sc - 12); store to P strip ----
            #pragma unroll
            for (int mf = 0; mf < 2; ++mf) {
                int rowb = mf * 16 + (lq << 2);
                #pragma unroll
                for (int nf = 0; nf < 4; ++nf) {
                    int col = nf * 16 + ln;
                    int ck = col >> 3, cl = col & 7;
                    #pragma unroll
                    for (int r = 0; r < 4; ++r) {
                        float p = __expf(fmaf(sf[mf][nf][r], sc, -SHIFT));
                        if (diag && (j0 + col > wrow0 + rowb + r)) p = 0.f;
                        int row = rowb + r;
                        psw[row * 72 + ((ck ^ (row & 7)) << 3) + cl] = f2bf(p);
                    }
                }
            }

            // ---- O += P V ; l += P * ones ----
            short8 ap0[2][2];
            #pragma unroll
            for (int mf = 0; mf < 2; ++mf)
                #pragma unroll
                for (int ks = 0; ks < 2; ++ks)
                    ap0[mf][ks] = *(const short8*)(psw + (mf * 16 + ln) * 72 + (((ks * 4 + lq) ^ (ln & 7)) << 3));
            #pragma unroll
            for (int ks = 0; ks < 2; ++ks) {
                lacc[0] = __builtin_amdgcn_mfma_f32_16x16x32_bf16(ap0[0][ks], onesb, lacc[0], 0, 0, 0);
                lacc[1] = __builtin_amdgcn_mfma_f32_16x16x32_bf16(ap0[1][ks], onesb, lacc[1], 0, 0, 0);
                #pragma unroll
                for (int nd = 0; nd < 8; ++nd) {
                    short8 bv = *(const short8*)(VsA + ks * 4096 + (nd * 16 + ln) * 32 + ((lq ^ swz) << 3));
                    o[0][nd] = __builtin_amdgcn_mfma_f32_16x16x32_bf16(ap0[0][ks], bv, o[0][nd], 0, 0, 0);
                    o[1][nd] = __builtin_amdgcn_mfma_f32_16x16x32_bf16(ap0[1][ks], bv, o[1][nd], 0, 0, 0);
                }
            }
        }
        __syncthreads();
    }

    // ---- normalize + write ctx (B,S,H,HD) ----
    int b = bh >> 4, h = bh & 15;
    #pragma unroll
    for (int mf = 0; mf < 2; ++mf)
        #pragma unroll
        for (int r = 0; r < 4; ++r) {
            float lv = __shfl(lacc[mf][r], lane & 48, 64); // broadcast col-0 lane of this 16-group
            float inv = 1.0f / lv;
            int q = wrow0 + mf * 16 + (lq << 2) + r;
            u16* cp = ctx + (((size_t)(b * Sc + q)) * Hc + h) * HDc + ln;
            #pragma unroll
            for (int nd = 0; nd < 8; ++nd)
                cp[nd * 16] = f2bf(o[mf][nd][r] * inv);
        }
}

extern "C" void kernel_launch(void* const* d_in, const int* in_sizes, int n_in,
                              void* d_out, int out_size, void* d_ws, size_t ws_size,
                              hipStream_t stream) {
    (void)in_sizes; (void)n_in; (void)out_size; (void)ws_size;
    const float* x  = (const float*)d_in[0];
    // d_in[1] = mask: causal, handled analytically
    const float* Wq = (const float*)d_in[2];
    const float* Wk = (const float*)d_in[3];
    const float* Wv = (const float*)d_in[4];
    const float* Wo = (const float*)d_in[5];

    char* w = (char*)d_ws;
    u16* Wt  = (u16*)w; w += (size_t)3 * Dc * Dc * 2;        // 24 MiB (QKV cat; reused for Wo)
    u16* Qb  = (u16*)w; w += (size_t)Bc * Hc * Sc * HDc * 2; // 16 MiB
    u16* Kb  = (u16*)w; w += (size_t)Bc * Hc * Sc * HDc * 2;
    u16* Vb  = (u16*)w; w += (size_t)Bc * Hc * Sc * HDc * 2; // V^T (B,H,HD,S)
    u16* ctx = (u16*)w; w += (size_t)Bc * Sc * Hc * HDc * 2;
    float* ctab = (float*)w; w += (size_t)Sc * 64 * 4;       // 0.5 MiB
    float* stab = (float*)w; w += (size_t)Sc * 64 * 4;       // 0.5 MiB
    u16* xb = (u16*)d_out; // bf16 x in d_out scratch (fp32 out = 2x the bytes)

    rope_tab_k<<<dim3(Sc * 64 / 256), 256, 0, stream>>>(ctab, stab);

    int nx = Bc * Sc * Dc;
    cvt_k<<<dim3(nx / 2048), 256, 0, stream>>>(x, xb, nx);

    // fused QKV: Wt = [WqT; WkT; WvT] (6144 x 2048)
    tcvt3_k<<<dim3(Dc / 64, Dc / 64, 3), 256, 0, stream>>>(Wq, Wk, Wv, Wt, Dc, Dc);
    gemm_bt<1><<<dim3(3 * Dc / 128, (Bc * Sc) / 128), 256, 0, stream>>>(
        xb, Wt, nullptr, Qb, Kb, Vb, ctab, stab, Bc * Sc, 3 * Dc, Dc);

    fattn_k<<<dim3(Bc * Hc, Sc / 128), 256, 0, stream>>>(Qb, Kb, Vb, ctx);

    tcvt3_k<<<dim3(Dc / 64, Dc / 64, 1), 256, 0, stream>>>(Wo, Wo, Wo, Wt, Dc, Dc);
    gemm_bt<2><<<dim3(Dc / 128, (Bc * Sc) / 128), 256, 0, stream>>>(
        ctx, Wt, (float*)d_out, nullptr, nullptr, nullptr, nullptr, nullptr, Bc * Sc, Dc, Dc);
}